// Round 1
// baseline (2268.228 us; speedup 1.0000x reference)
//
#include <hip/hip_runtime.h>

#define NU 100000
#define NI 50000
#define DD 64
#define ALPHA_C 1.0f
#define EPS_CLAMP 1e-6f

__device__ __forceinline__ float wsum(float v) {
#pragma unroll
  for (int m = 32; m >= 1; m >>= 1) v += __shfl_xor(v, m, 64);
  return v;
}

// --- K1: per-row inverse norms ---------------------------------------------
__global__ void k_norm(const float* __restrict__ x, float* __restrict__ inv_norm, int rows) {
  int lane = threadIdx.x & 63;
  int wid  = (blockIdx.x * blockDim.x + threadIdx.x) >> 6;
  int nw   = (gridDim.x * blockDim.x) >> 6;
  for (int r = wid; r < rows; r += nw) {
    float v = x[(size_t)r * DD + lane];
    float s = wsum(v * v);
    if (lane == 0) inv_norm[r] = 1.0f / fmaxf(sqrtf(s), 1e-12f);
  }
}

// --- K2: per-user edge counts ----------------------------------------------
__global__ void k_count(const int* __restrict__ u, float* __restrict__ cnt, int E) {
  int t = blockIdx.x * blockDim.x + threadIdx.x;
  int stride = gridDim.x * blockDim.x;
  for (int e = t; e < E; e += stride) atomicAdd(&cnt[u[e]], 1.0f);
}

// --- K3: column sums over items: sum_xi (normalized), sum_vi (raw) ----------
__global__ void k_item_sums(const float* __restrict__ x, const float* __restrict__ inv_norm,
                            float* __restrict__ sum_xi, float* __restrict__ sum_vi) {
  int lane = threadIdx.x; // blockDim.x == 64
  float sx = 0.f, sv = 0.f;
  for (int j = blockIdx.x; j < NI; j += gridDim.x) {
    int r = NU + j;
    float v = x[(size_t)r * DD + lane];
    sv += v;
    sx += v * inv_norm[r];
  }
  atomicAdd(&sum_xi[lane], sx);
  atomicAdd(&sum_vi[lane], sv);
}

// --- K4/K5: weighted outer-product accumulation (S and T) -------------------
// out[a,b] += sum_r w(r) * x[r,a] * x[r,b]
// mode 0: w = inv_norm[r]                  (S over items)
// mode 1: w = inv_norm[r]/max(NI-cnt[r],1) (T over users)
__global__ void k_outer(const float* __restrict__ x, const float* __restrict__ inv_norm,
                        const float* __restrict__ cnt, float* __restrict__ out,
                        int row0, int nrows, int mode) {
  __shared__ float row_s[DD];
  __shared__ float w_s;
  int t = threadIdx.x;          // 256 threads
  int a = t >> 2;               // 0..63
  int b0 = (t & 3) * 16;        // 0,16,32,48
  float acc[16];
#pragma unroll
  for (int k = 0; k < 16; ++k) acc[k] = 0.f;
  for (int rr = blockIdx.x; rr < nrows; rr += gridDim.x) {
    int r = row0 + rr;
    if (t < DD) row_s[t] = x[(size_t)r * DD + t];
    if (t == 0) {
      float w = inv_norm[r];
      if (mode == 1) w /= fmaxf((float)NI - cnt[r], 1.0f);
      w_s = w;
    }
    __syncthreads();
    float xa = row_s[a] * w_s;
#pragma unroll
    for (int k = 0; k < 16; ++k) acc[k] += xa * row_s[b0 + k];
    __syncthreads();
  }
#pragma unroll
  for (int k = 0; k < 16; ++k) atomicAdd(&out[a * DD + b0 + k], acc[k]);
}

// --- K6: edge pass 1 — user-side segments + per-edge dot --------------------
__global__ void k_edge1(const float* __restrict__ x, const float* __restrict__ inv_norm,
                        const int* __restrict__ u, const int* __restrict__ it,
                        float* __restrict__ sxi, float* __restrict__ svi,
                        float* __restrict__ xui, float* __restrict__ outA, int E) {
  int lane = threadIdx.x & 63;
  int wid  = (blockIdx.x * blockDim.x + threadIdx.x) >> 6;
  int nw   = (gridDim.x * blockDim.x) >> 6;
  for (int e = wid; e < E; e += nw) {
    int uu = u[e], ii = it[e];
    size_t ru = (size_t)uu * DD;
    size_t ri = (size_t)(NU + ii) * DD;
    float xu_l = x[ru + lane] * inv_norm[uu];
    float vi_l = x[ri + lane];
    float xi_l = vi_l * inv_norm[NU + ii];
    float d = wsum(xu_l * xi_l);
    if (lane == 0) xui[e] = d;
    atomicAdd(&sxi[ru + lane], xi_l);
    atomicAdd(&svi[ru + lane], vi_l);
    atomicAdd(&outA[ru + lane], d * vi_l);
  }
}

// --- K7: per-user pass -------------------------------------------------------
__global__ void k_user(const float* __restrict__ x, const float* __restrict__ inv_norm,
                       const float* __restrict__ cnt, const float* __restrict__ sxi,
                       const float* __restrict__ svi, const float* __restrict__ sum_xi,
                       const float* __restrict__ sum_vi, const float* __restrict__ Smat,
                       float* __restrict__ out, float* __restrict__ bpos, float* __restrict__ bneg,
                       float* __restrict__ Gx, float* __restrict__ Gv, float* __restrict__ Gb) {
  __shared__ float S_s[DD * DD];
  __shared__ float gx_s[DD], gv_s[DD], gb_s;
  for (int k = threadIdx.x; k < DD * DD; k += blockDim.x) S_s[k] = Smat[k];
  if (threadIdx.x < DD) { gx_s[threadIdx.x] = 0.f; gv_s[threadIdx.x] = 0.f; }
  if (threadIdx.x == 0) gb_s = 0.f;
  __syncthreads();

  int lane = threadIdx.x & 63;
  int wid  = blockIdx.x * (blockDim.x >> 6) + (threadIdx.x >> 6);
  int nw   = gridDim.x * (blockDim.x >> 6);
  for (int uu = wid; uu < NU; uu += nw) {
    size_t ru = (size_t)uu * DD;
    float c  = cnt[uu];
    float a1 = 1.0f / fmaxf(c, 1.0f);
    float a2 = 1.0f / fmaxf((float)NI - c, 1.0f);
    float v_l   = x[ru + lane];
    float xu_l  = v_l * inv_norm[uu];
    float sxi_l = sxi[ru + lane];
    float svi_l = svi[ru + lane];
    float A_l   = out[ru + lane];
    float bp = wsum(xu_l * sxi_l) * a1;
    float bn = wsum(xu_l * (sum_xi[lane] - sxi_l)) * a2;
    // xs = (xu @ S)[lane]
    float xs = 0.f;
#pragma unroll
    for (int a = 0; a < DD; ++a) xs += __shfl(xu_l, a, 64) * S_s[a * DD + lane];
    float svj_l = sum_vi[lane] - svi_l;
    float zu = A_l * a1 - svi_l * (bn - ALPHA_C) * a1
             + (xs - A_l) * a2 - svj_l * (bp + ALPHA_C) * a2;
    float du = bp - bn + ALPHA_C;                 // du1 == du2 algebraically
    float den = 2.0f * fmaxf(du, EPS_CLAMP);
    out[ru + lane] = zu / den;
    if (lane == 0) { bpos[uu] = bp; bneg[uu] = bn; }
    atomicAdd(&gx_s[lane], xu_l * a2);
    atomicAdd(&gv_s[lane], v_l * (bp + ALPHA_C) * a2);
    if (lane == 0) atomicAdd(&gb_s, (bp + ALPHA_C) * a2);
  }
  __syncthreads();
  if (threadIdx.x < DD) {
    atomicAdd(&Gx[threadIdx.x], gx_s[threadIdx.x]);
    atomicAdd(&Gv[threadIdx.x], gv_s[threadIdx.x]);
  }
  if (threadIdx.x == 0) atomicAdd(Gb, gb_s);
}

// --- K8: edge pass 2 — item-side segments ------------------------------------
__global__ void k_edge2(const float* __restrict__ x, const float* __restrict__ inv_norm,
                        const int* __restrict__ u, const int* __restrict__ it,
                        const float* __restrict__ cnt, const float* __restrict__ bpos,
                        const float* __restrict__ bneg, const float* __restrict__ xui,
                        float* __restrict__ P1, float* __restrict__ P2,
                        float* __restrict__ q1, float* __restrict__ q2,
                        float* __restrict__ outW, int E) {
  int lane = threadIdx.x & 63;
  int wid  = (blockIdx.x * blockDim.x + threadIdx.x) >> 6;
  int nw   = (gridDim.x * blockDim.x) >> 6;
  for (int e = wid; e < E; e += nw) {
    int uu = u[e], ii = it[e];
    float c  = cnt[uu];
    float a1 = 1.0f / fmaxf(c, 1.0f);
    float a2 = 1.0f / fmaxf((float)NI - c, 1.0f);
    float bp = bpos[uu], bn = bneg[uu];
    size_t ru = (size_t)uu * DD;
    float v_l  = x[ru + lane];
    float xu_l = v_l * inv_norm[uu];
    float xv = xui[e];
    float kk = xv * (a1 - a2) + (ALPHA_C - bn) * a1 + (bp + ALPHA_C) * a2;
    size_t ri = (size_t)ii * DD;
    atomicAdd(&P1[ri + lane], xu_l * a1);
    atomicAdd(&P2[ri + lane], xu_l * a2);
    atomicAdd(&outW[(size_t)(NU + ii) * DD + lane], v_l * kk);
    if (lane == 0) {
      atomicAdd(&q1[ii], (ALPHA_C - bn) * a1);
      atomicAdd(&q2[ii], (bp + ALPHA_C) * a2);
    }
  }
}

// --- K9: per-item pass --------------------------------------------------------
__global__ void k_item(const float* __restrict__ x, const float* __restrict__ inv_norm,
                       const float* __restrict__ P1, const float* __restrict__ P2,
                       const float* __restrict__ q1, const float* __restrict__ q2,
                       const float* __restrict__ Tmat, const float* __restrict__ Gx,
                       const float* __restrict__ Gv, const float* __restrict__ Gb,
                       float* __restrict__ out) {
  __shared__ float T_s[DD * DD];
  for (int k = threadIdx.x; k < DD * DD; k += blockDim.x) T_s[k] = Tmat[k];
  __syncthreads();
  int lane = threadIdx.x & 63;
  int wid  = blockIdx.x * (blockDim.x >> 6) + (threadIdx.x >> 6);
  int nw   = gridDim.x * (blockDim.x >> 6);
  float gb = *Gb;
  for (int j = wid; j < NI; j += nw) {
    int r = NU + j;
    size_t rr = (size_t)r * DD;
    size_t rj = (size_t)j * DD;
    float xi_l = x[rr + lane] * inv_norm[r];
    float p1 = P1[rj + lane];
    float p2 = P2[rj + lane];
    float di1 = wsum(xi_l * p1) + q1[j];
    float di2 = -wsum(xi_l * (Gx[lane] - p2)) + gb - q2[j];
    float xt = 0.f;
#pragma unroll
    for (int a = 0; a < DD; ++a) xt += __shfl(xi_l, a, 64) * T_s[a * DD + lane];
    float zi = out[rr + lane] + xt - Gv[lane];
    out[rr + lane] = zi / (fmaxf(di1, EPS_CLAMP) + fmaxf(di2, EPS_CLAMP));
  }
}

extern "C" void kernel_launch(void* const* d_in, const int* in_sizes, int n_in,
                              void* d_out, int out_size, void* d_ws, size_t ws_size,
                              hipStream_t stream) {
  const float* x = (const float*)d_in[0];
  const int*   u = (const int*)d_in[1];
  const int*   it = (const int*)d_in[2];
  float* out = (float*)d_out;
  const int E = in_sizes[1];
  const int ROWS = NU + NI;

  // workspace layout (floats)
  float* ws = (float*)d_ws;
  size_t off = 0;
  float* inv_norm = ws + off; off += 150016;
  float* cnt      = ws + off; off += 100032;
  float* sum_xi   = ws + off; off += 64;
  float* sum_vi   = ws + off; off += 64;
  float* Gx       = ws + off; off += 64;
  float* Gv       = ws + off; off += 64;
  float* Gb       = ws + off; off += 16;
  float* Smat     = ws + off; off += 4096;
  float* Tmat     = ws + off; off += 4096;
  float* bpos     = ws + off; off += 100032;
  float* bneg     = ws + off; off += 100032;
  float* sxi      = ws + off; off += (size_t)NU * DD;
  float* svi      = ws + off; off += (size_t)NU * DD;
  float* xui      = ws + off; off += 1000064;
  float* P1       = ws + off; off += (size_t)NI * DD;
  float* P2       = ws + off; off += (size_t)NI * DD;
  float* q1       = ws + off; off += 50048;
  float* q2       = ws + off; off += 50048;

  hipMemsetAsync(d_ws, 0, off * sizeof(float), stream);
  hipMemsetAsync(d_out, 0, (size_t)ROWS * DD * sizeof(float), stream);

  k_norm<<<2048, 256, 0, stream>>>(x, inv_norm, ROWS);
  k_count<<<1024, 256, 0, stream>>>(u, cnt, E);
  k_item_sums<<<256, 64, 0, stream>>>(x, inv_norm, sum_xi, sum_vi);
  k_outer<<<128, 256, 0, stream>>>(x, inv_norm, cnt, Smat, NU, NI, 0);
  k_outer<<<256, 256, 0, stream>>>(x, inv_norm, cnt, Tmat, 0, NU, 1);
  k_edge1<<<8192, 256, 0, stream>>>(x, inv_norm, u, it, sxi, svi, xui, out, E);
  k_user<<<1024, 256, 0, stream>>>(x, inv_norm, cnt, sxi, svi, sum_xi, sum_vi, Smat,
                                   out, bpos, bneg, Gx, Gv, Gb);
  k_edge2<<<8192, 256, 0, stream>>>(x, inv_norm, u, it, cnt, bpos, bneg, xui,
                                    P1, P2, q1, q2, out, E);
  k_item<<<512, 256, 0, stream>>>(x, inv_norm, P1, P2, q1, q2, Tmat, Gx, Gv, Gb, out);
}

// Round 2
// 1766.060 us; speedup vs baseline: 1.2843x; 1.2843x over previous
//
#include <hip/hip_runtime.h>

#define NU 100000
#define NI 50000
#define DD 64
#define ALPHA_C 1.0f
#define EPS_CLAMP 1e-6f

__device__ __forceinline__ float wsum(float v) {
#pragma unroll
  for (int m = 32; m >= 1; m >>= 1) v += __shfl_xor(v, m, 64);
  return v;
}

// --- K1: per-row inverse norms ---------------------------------------------
__global__ void k_norm(const float* __restrict__ x, float* __restrict__ inv_norm, int rows) {
  int lane = threadIdx.x & 63;
  int wid  = (blockIdx.x * blockDim.x + threadIdx.x) >> 6;
  int nw   = (gridDim.x * blockDim.x) >> 6;
  for (int r = wid; r < rows; r += nw) {
    float v = x[(size_t)r * DD + lane];
    float s = wsum(v * v);
    if (lane == 0) inv_norm[r] = 1.0f / fmaxf(sqrtf(s), 1e-12f);
  }
}

// --- K2: degree counts (int) ------------------------------------------------
__global__ void k_count(const int* __restrict__ u, const int* __restrict__ it,
                        int* __restrict__ du, int* __restrict__ di, int E) {
  int t = blockIdx.x * blockDim.x + threadIdx.x;
  int stride = gridDim.x * blockDim.x;
  for (int e = t; e < E; e += stride) {
    atomicAdd(&du[u[e]], 1);
    atomicAdd(&di[it[e]], 1);
  }
}

// --- K3: single-block exclusive scan (8 elems/thread) ------------------------
__global__ void k_scan(const int* __restrict__ cnt, int n,
                       int* __restrict__ off, int* __restrict__ cur) {
  __shared__ int wsum_s[16];
  __shared__ int carry_s;
  int t = threadIdx.x, lane = t & 63, wv = t >> 6;
  if (t == 0) carry_s = 0;
  __syncthreads();
  for (int base = 0; base < n; base += 1024 * 8) {
    int v[8];
    int s = 0;
    int i0 = base + t * 8;
#pragma unroll
    for (int k = 0; k < 8; ++k) {
      int idx = i0 + k;
      v[k] = (idx < n) ? cnt[idx] : 0;
      s += v[k];
    }
    int incl = s;
#pragma unroll
    for (int d = 1; d < 64; d <<= 1) {
      int t2 = __shfl_up(incl, d, 64);
      if (lane >= d) incl += t2;
    }
    if (lane == 63) wsum_s[wv] = incl;
    __syncthreads();
    int woff = 0, total = 0;
#pragma unroll
    for (int w = 0; w < 16; ++w) {
      int ws_v = wsum_s[w];
      woff += (w < wv) ? ws_v : 0;
      total += ws_v;
    }
    int excl = carry_s + woff + incl - s;
#pragma unroll
    for (int k = 0; k < 8; ++k) {
      int idx = i0 + k;
      if (idx < n) { off[idx] = excl; cur[idx] = excl; }
      excl += v[k];
    }
    __syncthreads();
    if (t == 0) carry_s += total;
    __syncthreads();
  }
  if (t == 0) off[n] = carry_s;
}

// --- K4: scatter edge ids into CSR lists -------------------------------------
__global__ void k_scatter(const int* __restrict__ u, const int* __restrict__ it, int E,
                          int* __restrict__ ucur, int* __restrict__ icur,
                          int* __restrict__ uedge, int* __restrict__ iedge) {
  int t = blockIdx.x * blockDim.x + threadIdx.x;
  int stride = gridDim.x * blockDim.x;
  for (int e = t; e < E; e += stride) {
    int pu = atomicAdd(&ucur[u[e]], 1);
    uedge[pu] = e;
    int pi = atomicAdd(&icur[it[e]], 1);
    iedge[pi] = e;
  }
}

// --- K5: column sums over items: sum_xi (normalized), sum_vi (raw) -----------
__global__ void k_item_sums(const float* __restrict__ x, const float* __restrict__ inv_norm,
                            float* __restrict__ sum_xi, float* __restrict__ sum_vi) {
  int lane = threadIdx.x; // blockDim.x == 64
  float sx = 0.f, sv = 0.f;
  for (int j = blockIdx.x; j < NI; j += gridDim.x) {
    int r = NU + j;
    float v = x[(size_t)r * DD + lane];
    sv += v;
    sx += v * inv_norm[r];
  }
  atomicAdd(&sum_xi[lane], sx);
  atomicAdd(&sum_vi[lane], sv);
}

// --- K6/K7: weighted symmetric outer products S, T ----------------------------
// mode 0: w = inv_norm[r]                         (S over item rows)
// mode 1: w = inv_norm[r]/max(NI-du[r],1)         (T over user rows)
__global__ void k_outer(const float* __restrict__ x, const float* __restrict__ inv_norm,
                        const int* __restrict__ du, float* __restrict__ out,
                        int row0, int nrows, int mode) {
  __shared__ float row_s[DD];
  __shared__ float w_s;
  int t = threadIdx.x;          // 256 threads
  int a = t >> 2;               // 0..63
  int b0 = (t & 3) * 16;        // 0,16,32,48
  float acc[16];
#pragma unroll
  for (int k = 0; k < 16; ++k) acc[k] = 0.f;
  for (int rr = blockIdx.x; rr < nrows; rr += gridDim.x) {
    int r = row0 + rr;
    if (t < DD) row_s[t] = x[(size_t)r * DD + t];
    if (t == 0) {
      float w = inv_norm[r];
      if (mode == 1) w /= fmaxf((float)NI - (float)du[r], 1.0f);
      w_s = w;
    }
    __syncthreads();
    float xa = row_s[a] * w_s;
#pragma unroll
    for (int k = 0; k < 16; ++k) acc[k] += xa * row_s[b0 + k];
    __syncthreads();
  }
#pragma unroll
  for (int k = 0; k < 16; ++k) atomicAdd(&out[a * DD + b0 + k], acc[k]);
}

// --- K8: per-user pass (CSR gather, no vector atomics) ------------------------
__global__ void k_user(const float* __restrict__ x, const float* __restrict__ inv_norm,
                       const int* __restrict__ uoff, const int* __restrict__ uedge,
                       const int* __restrict__ it, const float* __restrict__ sum_xi,
                       const float* __restrict__ sum_vi, const float* __restrict__ Smat,
                       float* __restrict__ xui, float4* __restrict__ usc,
                       float* __restrict__ out) {
  __shared__ float S_s[DD * DD];
  for (int k = threadIdx.x; k < DD * DD; k += blockDim.x) S_s[k] = Smat[k];
  __syncthreads();
  int lane = threadIdx.x & 63;
  int wid  = blockIdx.x * (blockDim.x >> 6) + (threadIdx.x >> 6);
  int nw   = gridDim.x * (blockDim.x >> 6);
  float sxl = sum_xi[lane];
  float svl = sum_vi[lane];
  for (int uu = wid; uu < NU; uu += nw) {
    size_t ru = (size_t)uu * DD;
    int beg = uoff[uu], end = uoff[uu + 1];
    float deg = (float)(end - beg);
    float a1 = 1.0f / fmaxf(deg, 1.0f);
    float a2 = 1.0f / fmaxf((float)NI - deg, 1.0f);
    float v_l  = x[ru + lane];
    float xu_l = v_l * inv_norm[uu];
    float A_l = 0.f, sv_l = 0.f, sA = 0.f;
    for (int k = beg; k < end; ++k) {
      int e  = uedge[k];
      int ii = it[e];
      size_t ri = (size_t)(NU + ii) * DD;
      float vi_l = x[ri + lane];
      float xi_l = vi_l * inv_norm[NU + ii];
      float d = wsum(xu_l * xi_l);
      if (lane == 0) xui[e] = d;
      A_l  += d * vi_l;
      sv_l += vi_l;
      sA   += d;
    }
    float bp = sA * a1;
    float bn = (wsum(xu_l * sxl) - sA) * a2;
    float s1 = (ALPHA_C - bn) * a1;
    float s2 = (bp + ALPHA_C) * a2;
    if (lane == 0) usc[uu] = make_float4(a1, a2, s1, s2);
    float xs = 0.f;
#pragma unroll
    for (int a = 0; a < DD; ++a) xs += __shfl(xu_l, a, 64) * S_s[a * DD + lane];
    float zu = A_l * (a1 - a2) + sv_l * (s1 + s2) + xs * a2 - svl * s2;
    float den = 2.0f * fmaxf(bp - bn + ALPHA_C, EPS_CLAMP);
    out[ru + lane] = zu / den;
  }
}

// --- K9: global user sums Gx, Gv, Gb ------------------------------------------
__global__ void k_glob(const float* __restrict__ x, const float* __restrict__ inv_norm,
                       const float4* __restrict__ usc,
                       float* __restrict__ Gx, float* __restrict__ Gv, float* __restrict__ Gb) {
  __shared__ float gx_s[DD], gv_s[DD], gb_s;
  if (threadIdx.x < DD) { gx_s[threadIdx.x] = 0.f; gv_s[threadIdx.x] = 0.f; }
  if (threadIdx.x == 0) gb_s = 0.f;
  __syncthreads();
  int lane = threadIdx.x & 63;
  int wid  = blockIdx.x * (blockDim.x >> 6) + (threadIdx.x >> 6);
  int nw   = gridDim.x * (blockDim.x >> 6);
  float gx = 0.f, gv = 0.f, gb = 0.f;
  for (int uu = wid; uu < NU; uu += nw) {
    float4 c = usc[uu];
    float v_l = x[(size_t)uu * DD + lane];
    gx += v_l * inv_norm[uu] * c.y;  // xu * a2
    gv += v_l * c.w;                 // vu * s2
    if (lane == 0) gb += c.w;
  }
  atomicAdd(&gx_s[lane], gx);
  atomicAdd(&gv_s[lane], gv);
  if (lane == 0) atomicAdd(&gb_s, gb);
  __syncthreads();
  if (threadIdx.x < DD) {
    atomicAdd(&Gx[threadIdx.x], gx_s[threadIdx.x]);
    atomicAdd(&Gv[threadIdx.x], gv_s[threadIdx.x]);
  }
  if (threadIdx.x == 0) atomicAdd(Gb, gb_s);
}

// --- K10: per-item pass (CSR gather) -------------------------------------------
__global__ void k_item(const float* __restrict__ x, const float* __restrict__ inv_norm,
                       const int* __restrict__ ioff, const int* __restrict__ iedge,
                       const int* __restrict__ u, const float* __restrict__ xui,
                       const float4* __restrict__ usc, const float* __restrict__ Tmat,
                       const float* __restrict__ Gx, const float* __restrict__ Gv,
                       const float* __restrict__ Gb, float* __restrict__ out) {
  __shared__ float T_s[DD * DD];
  for (int k = threadIdx.x; k < DD * DD; k += blockDim.x) T_s[k] = Tmat[k];
  __syncthreads();
  int lane = threadIdx.x & 63;
  int wid  = blockIdx.x * (blockDim.x >> 6) + (threadIdx.x >> 6);
  int nw   = gridDim.x * (blockDim.x >> 6);
  float gxl = Gx[lane];
  float gvl = Gv[lane];
  float gb  = *Gb;
  for (int j = wid; j < NI; j += nw) {
    int r = NU + j;
    size_t rr = (size_t)r * DD;
    float xiv  = x[rr + lane];
    float xi_l = xiv * inv_norm[r];
    int beg = ioff[j], end = ioff[j + 1];
    float W_l = 0.f, q1 = 0.f, q2 = 0.f;
    for (int k = beg; k < end; ++k) {
      int e  = iedge[k];
      int uu = u[e];
      float xv = xui[e];
      float4 c = usc[uu];
      float g = xv * (c.x - c.y) + c.z + c.w;
      W_l += x[(size_t)uu * DD + lane] * g;
      q1  += xv * c.x + c.z;
      q2  += xv * c.y - c.w;
    }
    float di1 = q1;
    float di2 = -wsum(xi_l * gxl) + q2 + gb;
    float xt = 0.f;
#pragma unroll
    for (int a = 0; a < DD; ++a) xt += __shfl(xi_l, a, 64) * T_s[a * DD + lane];
    float zi = W_l + xt - gvl;
    out[rr + lane] = zi / (fmaxf(di1, EPS_CLAMP) + fmaxf(di2, EPS_CLAMP));
  }
}

extern "C" void kernel_launch(void* const* d_in, const int* in_sizes, int n_in,
                              void* d_out, int out_size, void* d_ws, size_t ws_size,
                              hipStream_t stream) {
  const float* x  = (const float*)d_in[0];
  const int*   u  = (const int*)d_in[1];
  const int*   it = (const int*)d_in[2];
  float* out = (float*)d_out;
  const int E = in_sizes[1];
  const int ROWS = NU + NI;

  // ---- workspace layout (floats/ints, all 16-element aligned) ----
  char* wsb = (char*)d_ws;
  size_t off = 0;
  auto alloc = [&](size_t elems) { void* p = wsb + off; off += elems * 4; return p; };

  // zero-init region (contiguous, first)
  int*   du     = (int*)alloc(100016);
  int*   di     = (int*)alloc(50016);
  float* sum_xi = (float*)alloc(64);
  float* sum_vi = (float*)alloc(64);
  float* Gx     = (float*)alloc(64);
  float* Gv     = (float*)alloc(64);
  float* Gb     = (float*)alloc(16);
  float* Smat   = (float*)alloc(4096);
  float* Tmat   = (float*)alloc(4096);
  size_t zero_bytes = off;

  float*  inv_norm = (float*)alloc(150016);
  int*    uoff     = (int*)alloc(100016);
  int*    ucur     = (int*)alloc(100016);
  int*    ioff     = (int*)alloc(50016);
  int*    icur     = (int*)alloc(50016);
  int*    uedge    = (int*)alloc(1000000);
  int*    iedge    = (int*)alloc(1000000);
  float*  xui      = (float*)alloc(1000000);
  float4* usc      = (float4*)alloc(400000);

  hipMemsetAsync(d_ws, 0, zero_bytes, stream);

  k_norm<<<2048, 256, 0, stream>>>(x, inv_norm, ROWS);
  k_count<<<2048, 256, 0, stream>>>(u, it, du, di, E);
  k_scan<<<1, 1024, 0, stream>>>(du, NU, uoff, ucur);
  k_scan<<<1, 1024, 0, stream>>>(di, NI, ioff, icur);
  k_scatter<<<2048, 256, 0, stream>>>(u, it, E, ucur, icur, uedge, iedge);
  k_item_sums<<<512, 64, 0, stream>>>(x, inv_norm, sum_xi, sum_vi);
  k_outer<<<256, 256, 0, stream>>>(x, inv_norm, du, Smat, NU, NI, 0);
  k_outer<<<256, 256, 0, stream>>>(x, inv_norm, du, Tmat, 0, NU, 1);
  k_user<<<2048, 256, 0, stream>>>(x, inv_norm, uoff, uedge, it, sum_xi, sum_vi,
                                   Smat, xui, usc, out);
  k_glob<<<512, 256, 0, stream>>>(x, inv_norm, usc, Gx, Gv, Gb);
  k_item<<<1024, 256, 0, stream>>>(x, inv_norm, ioff, iedge, u, xui, usc, Tmat,
                                   Gx, Gv, Gb, out);
}

// Round 3
// 1492.691 us; speedup vs baseline: 1.5196x; 1.1831x over previous
//
#include <hip/hip_runtime.h>

#define NU 100000
#define NI 50000
#define DD 64
#define ALPHA_C 1.0f
#define EPS_CLAMP 1e-6f

__device__ __forceinline__ float wsum(float v) {
#pragma unroll
  for (int m = 32; m >= 1; m >>= 1) v += __shfl_xor(v, m, 64);
  return v;
}

// --- K1: per-row inverse norms ---------------------------------------------
__global__ void k_norm(const float* __restrict__ x, float* __restrict__ inv_norm, int rows) {
  int lane = threadIdx.x & 63;
  int wid  = (blockIdx.x * blockDim.x + threadIdx.x) >> 6;
  int nw   = (gridDim.x * blockDim.x) >> 6;
  for (int r = wid; r < rows; r += nw) {
    float v = x[(size_t)r * DD + lane];
    float s = wsum(v * v);
    if (lane == 0) inv_norm[r] = 1.0f / fmaxf(sqrtf(s), 1e-12f);
  }
}

// --- K2: degree counts (int) ------------------------------------------------
__global__ void k_count(const int* __restrict__ u, const int* __restrict__ it,
                        int* __restrict__ du, int* __restrict__ di, int E) {
  int t = blockIdx.x * blockDim.x + threadIdx.x;
  int stride = gridDim.x * blockDim.x;
  for (int e = t; e < E; e += stride) {
    atomicAdd(&du[u[e]], 1);
    atomicAdd(&di[it[e]], 1);
  }
}

// --- K3: two single-block exclusive scans, run concurrently (gridDim=2) ------
__global__ void k_scan2(const int* __restrict__ cnt0, int n0, int* __restrict__ off0, int* __restrict__ cur0,
                        const int* __restrict__ cnt1, int n1, int* __restrict__ off1, int* __restrict__ cur1) {
  const int* cnt = blockIdx.x ? cnt1 : cnt0;
  int n          = blockIdx.x ? n1   : n0;
  int* off       = blockIdx.x ? off1 : off0;
  int* cur       = blockIdx.x ? cur1 : cur0;
  __shared__ int wsum_s[16];
  __shared__ int carry_s;
  int t = threadIdx.x, lane = t & 63, wv = t >> 6;
  if (t == 0) carry_s = 0;
  __syncthreads();
  for (int base = 0; base < n; base += 1024 * 8) {
    int v[8];
    int s = 0;
    int i0 = base + t * 8;
#pragma unroll
    for (int k = 0; k < 8; ++k) {
      int idx = i0 + k;
      v[k] = (idx < n) ? cnt[idx] : 0;
      s += v[k];
    }
    int incl = s;
#pragma unroll
    for (int d = 1; d < 64; d <<= 1) {
      int t2 = __shfl_up(incl, d, 64);
      if (lane >= d) incl += t2;
    }
    if (lane == 63) wsum_s[wv] = incl;
    __syncthreads();
    int woff = 0, total = 0;
#pragma unroll
    for (int w = 0; w < 16; ++w) {
      int ws_v = wsum_s[w];
      woff += (w < wv) ? ws_v : 0;
      total += ws_v;
    }
    int excl = carry_s + woff + incl - s;
#pragma unroll
    for (int k = 0; k < 8; ++k) {
      int idx = i0 + k;
      if (idx < n) { off[idx] = excl; cur[idx] = excl; }
      excl += v[k];
    }
    __syncthreads();
    if (t == 0) carry_s += total;
    __syncthreads();
  }
  if (t == 0) off[n] = carry_s;
}

// --- K4: scatter edge ids into CSR lists -------------------------------------
__global__ void k_scatter(const int* __restrict__ u, const int* __restrict__ it, int E,
                          int* __restrict__ ucur, int* __restrict__ icur,
                          int* __restrict__ uedge, int* __restrict__ iedge) {
  int t = blockIdx.x * blockDim.x + threadIdx.x;
  int stride = gridDim.x * blockDim.x;
  for (int e = t; e < E; e += stride) {
    int pu = atomicAdd(&ucur[u[e]], 1);
    uedge[pu] = e;
    int pi = atomicAdd(&icur[it[e]], 1);
    iedge[pi] = e;
  }
}

// --- K5: column sums over items: sum_xi (normalized), sum_vi (raw) -----------
__global__ void k_item_sums(const float* __restrict__ x, const float* __restrict__ inv_norm,
                            float* __restrict__ sum_xi, float* __restrict__ sum_vi) {
  int lane = threadIdx.x; // blockDim.x == 64
  float sx = 0.f, sv = 0.f;
  for (int j = blockIdx.x; j < NI; j += gridDim.x) {
    int r = NU + j;
    float v = x[(size_t)r * DD + lane];
    sv += v;
    sx += v * inv_norm[r];
  }
  atomicAdd(&sum_xi[lane], sx);
  atomicAdd(&sum_vi[lane], sv);
}

// --- K6: fused weighted outer products S (items) and T (users) ----------------
// blocks [0,gS): S += sum_j inv_norm[NU+j] * xi_j xi_j^T        (NI rows)
// blocks [gS,G): T += sum_u inv_norm[u]/max(NI-du[u],1) vu vu^T  (NU rows)
// 16 rows staged per chunk; 256 threads; thread t owns (a = t>>2, c0 = (t&3)*16).
__global__ void k_outer2(const float* __restrict__ x, const float* __restrict__ inv_norm,
                         const int* __restrict__ du,
                         float* __restrict__ Smat, float* __restrict__ Tmat, int gS) {
  bool isT = (int)blockIdx.x >= gS;
  int bfirst = isT ? gS : 0;
  int nb     = isT ? ((int)gridDim.x - gS) : gS;
  int nch    = isT ? (NU / 16) : (NI / 16);
  int row0   = isT ? 0 : NU;
  float* out = isT ? Tmat : Smat;

  __shared__ float rows_s[16 * DD];
  __shared__ float w_s[16];
  int t  = threadIdx.x;
  int a  = t >> 2;
  int c0 = (t & 3) * 16;
  float acc[16];
#pragma unroll
  for (int k = 0; k < 16; ++k) acc[k] = 0.f;

  for (int ch = (int)blockIdx.x - bfirst; ch < nch; ch += nb) {
    int rbase = row0 + ch * 16;
    ((float4*)rows_s)[t] = ((const float4*)(x + (size_t)rbase * DD))[t];
    if (t < 16) {
      int r = rbase + t;
      float w = inv_norm[r];
      if (isT) w /= fmaxf((float)NI - (float)du[r], 1.0f);
      w_s[t] = w;
    }
    __syncthreads();
#pragma unroll
    for (int r = 0; r < 16; ++r) {
      float xa = rows_s[r * DD + a] * w_s[r];
#pragma unroll
      for (int k = 0; k < 16; ++k) acc[k] += xa * rows_s[r * DD + c0 + k];
    }
    __syncthreads();
  }
#pragma unroll
  for (int k = 0; k < 16; ++k) atomicAdd(&out[a * DD + c0 + k], acc[k]);
}

// --- K7: per-user pass (CSR gather) + fused global sums Gx,Gv,Gb ---------------
__global__ void k_user(const float* __restrict__ x, const float* __restrict__ inv_norm,
                       const int* __restrict__ uoff, const int* __restrict__ uedge,
                       const int* __restrict__ it, const float* __restrict__ sum_xi,
                       const float* __restrict__ sum_vi, const float* __restrict__ Smat,
                       float* __restrict__ xui, float4* __restrict__ usc,
                       float* __restrict__ out,
                       float* __restrict__ Gx, float* __restrict__ Gv, float* __restrict__ Gb) {
  __shared__ float S_s[DD * DD];
  __shared__ float gx_s[DD], gv_s[DD], gb_s;
  for (int k = threadIdx.x; k < DD * DD; k += blockDim.x) S_s[k] = Smat[k];
  if (threadIdx.x < DD) { gx_s[threadIdx.x] = 0.f; gv_s[threadIdx.x] = 0.f; }
  if (threadIdx.x == 0) gb_s = 0.f;
  __syncthreads();
  int lane = threadIdx.x & 63;
  int wid  = blockIdx.x * (blockDim.x >> 6) + (threadIdx.x >> 6);
  int nw   = gridDim.x * (blockDim.x >> 6);
  float sxl = sum_xi[lane];
  float svl = sum_vi[lane];
  float gx = 0.f, gv = 0.f, gb = 0.f;
  for (int uu = wid; uu < NU; uu += nw) {
    size_t ru = (size_t)uu * DD;
    int beg = uoff[uu], end = uoff[uu + 1];
    float deg = (float)(end - beg);
    float a1 = 1.0f / fmaxf(deg, 1.0f);
    float a2 = 1.0f / fmaxf((float)NI - deg, 1.0f);
    float v_l  = x[ru + lane];
    float xu_l = v_l * inv_norm[uu];
    float A_l = 0.f, sv_l = 0.f, sA = 0.f;
    for (int k = beg; k < end; ++k) {
      int e  = uedge[k];
      int ii = it[e];
      size_t ri = (size_t)(NU + ii) * DD;
      float vi_l = x[ri + lane];
      float xi_l = vi_l * inv_norm[NU + ii];
      float d = wsum(xu_l * xi_l);
      if (lane == 0) xui[e] = d;
      A_l  += d * vi_l;
      sv_l += vi_l;
      sA   += d;
    }
    float bp = sA * a1;
    float bn = (wsum(xu_l * sxl) - sA) * a2;
    float s1 = (ALPHA_C - bn) * a1;
    float s2 = (bp + ALPHA_C) * a2;
    if (lane == 0) usc[uu] = make_float4(a1, a2, s1, s2);
    float xs = 0.f;
#pragma unroll
    for (int a = 0; a < DD; ++a) xs += __shfl(xu_l, a, 64) * S_s[a * DD + lane];
    float zu = A_l * (a1 - a2) + sv_l * (s1 + s2) + xs * a2 - svl * s2;
    float den = 2.0f * fmaxf(bp - bn + ALPHA_C, EPS_CLAMP);
    out[ru + lane] = zu / den;
    gx += xu_l * a2;
    gv += v_l * s2;
    if (lane == 0) gb += s2;
  }
  atomicAdd(&gx_s[lane], gx);
  atomicAdd(&gv_s[lane], gv);
  if (lane == 0) atomicAdd(&gb_s, gb);
  __syncthreads();
  if (threadIdx.x < DD) {
    atomicAdd(&Gx[threadIdx.x], gx_s[threadIdx.x]);
    atomicAdd(&Gv[threadIdx.x], gv_s[threadIdx.x]);
  }
  if (threadIdx.x == 0) atomicAdd(Gb, gb_s);
}

// --- K8: per-item pass (CSR gather) -------------------------------------------
__global__ void k_item(const float* __restrict__ x, const float* __restrict__ inv_norm,
                       const int* __restrict__ ioff, const int* __restrict__ iedge,
                       const int* __restrict__ u, const float* __restrict__ xui,
                       const float4* __restrict__ usc, const float* __restrict__ Tmat,
                       const float* __restrict__ Gx, const float* __restrict__ Gv,
                       const float* __restrict__ Gb, float* __restrict__ out) {
  __shared__ float T_s[DD * DD];
  for (int k = threadIdx.x; k < DD * DD; k += blockDim.x) T_s[k] = Tmat[k];
  __syncthreads();
  int lane = threadIdx.x & 63;
  int wid  = blockIdx.x * (blockDim.x >> 6) + (threadIdx.x >> 6);
  int nw   = gridDim.x * (blockDim.x >> 6);
  float gxl = Gx[lane];
  float gvl = Gv[lane];
  float gb  = *Gb;
  for (int j = wid; j < NI; j += nw) {
    int r = NU + j;
    size_t rr = (size_t)r * DD;
    float xiv  = x[rr + lane];
    float xi_l = xiv * inv_norm[r];
    int beg = ioff[j], end = ioff[j + 1];
    float W_l = 0.f, q1 = 0.f, q2 = 0.f;
    for (int k = beg; k < end; ++k) {
      int e  = iedge[k];
      int uu = u[e];
      float xv = xui[e];
      float4 c = usc[uu];
      float g = xv * (c.x - c.y) + c.z + c.w;
      W_l += x[(size_t)uu * DD + lane] * g;
      q1  += xv * c.x + c.z;
      q2  += xv * c.y - c.w;
    }
    float di1 = q1;
    float di2 = -wsum(xi_l * gxl) + q2 + gb;
    float xt = 0.f;
#pragma unroll
    for (int a = 0; a < DD; ++a) xt += __shfl(xi_l, a, 64) * T_s[a * DD + lane];
    float zi = W_l + xt - gvl;
    out[rr + lane] = zi / (fmaxf(di1, EPS_CLAMP) + fmaxf(di2, EPS_CLAMP));
  }
}

extern "C" void kernel_launch(void* const* d_in, const int* in_sizes, int n_in,
                              void* d_out, int out_size, void* d_ws, size_t ws_size,
                              hipStream_t stream) {
  const float* x  = (const float*)d_in[0];
  const int*   u  = (const int*)d_in[1];
  const int*   it = (const int*)d_in[2];
  float* out = (float*)d_out;
  const int E = in_sizes[1];
  const int ROWS = NU + NI;

  char* wsb = (char*)d_ws;
  size_t off = 0;
  auto alloc = [&](size_t elems) { void* p = wsb + off; off += elems * 4; return p; };

  // zero-init region (contiguous, first)
  int*   du     = (int*)alloc(100016);
  int*   di     = (int*)alloc(50016);
  float* sum_xi = (float*)alloc(64);
  float* sum_vi = (float*)alloc(64);
  float* Gx     = (float*)alloc(64);
  float* Gv     = (float*)alloc(64);
  float* Gb     = (float*)alloc(16);
  float* Smat   = (float*)alloc(4096);
  float* Tmat   = (float*)alloc(4096);
  size_t zero_bytes = off;

  float*  inv_norm = (float*)alloc(150016);
  int*    uoff     = (int*)alloc(100016);
  int*    ucur     = (int*)alloc(100016);
  int*    ioff     = (int*)alloc(50016);
  int*    icur     = (int*)alloc(50016);
  int*    uedge    = (int*)alloc(1000000);
  int*    iedge    = (int*)alloc(1000000);
  float*  xui      = (float*)alloc(1000000);
  float4* usc      = (float4*)alloc(400000);

  hipMemsetAsync(d_ws, 0, zero_bytes, stream);

  k_norm<<<2048, 256, 0, stream>>>(x, inv_norm, ROWS);
  k_count<<<2048, 256, 0, stream>>>(u, it, du, di, E);
  k_scan2<<<2, 1024, 0, stream>>>(du, NU, uoff, ucur, di, NI, ioff, icur);
  k_scatter<<<2048, 256, 0, stream>>>(u, it, E, ucur, icur, uedge, iedge);
  k_item_sums<<<512, 64, 0, stream>>>(x, inv_norm, sum_xi, sum_vi);
  k_outer2<<<768, 256, 0, stream>>>(x, inv_norm, du, Smat, Tmat, 256);
  k_user<<<2048, 256, 0, stream>>>(x, inv_norm, uoff, uedge, it, sum_xi, sum_vi,
                                   Smat, xui, usc, out, Gx, Gv, Gb);
  k_item<<<1600, 256, 0, stream>>>(x, inv_norm, ioff, iedge, u, xui, usc, Tmat,
                                   Gx, Gv, Gb, out);
}

// Round 4
// 1081.222 us; speedup vs baseline: 2.0978x; 1.3806x over previous
//
#include <hip/hip_runtime.h>

#define NU 100000
#define NI 50000
#define DD 64
#define ALPHA_C 1.0f
#define EPS_CLAMP 1e-6f

__device__ __forceinline__ float wsum(float v) {
#pragma unroll
  for (int m = 32; m >= 1; m >>= 1) v += __shfl_xor(v, m, 64);
  return v;
}

// --- K1: per-row inverse norms ---------------------------------------------
__global__ void k_norm(const float* __restrict__ x, float* __restrict__ inv_norm, int rows) {
  int lane = threadIdx.x & 63;
  int wid  = (blockIdx.x * blockDim.x + threadIdx.x) >> 6;
  int nw   = (gridDim.x * blockDim.x) >> 6;
  for (int r = wid; r < rows; r += nw) {
    float v = x[(size_t)r * DD + lane];
    float s = wsum(v * v);
    if (lane == 0) inv_norm[r] = 1.0f / fmaxf(sqrtf(s), 1e-12f);
  }
}

// --- K2: degree counts (int) ------------------------------------------------
__global__ void k_count(const int* __restrict__ u, const int* __restrict__ it,
                        int* __restrict__ du, int* __restrict__ di, int E) {
  int t = blockIdx.x * blockDim.x + threadIdx.x;
  int stride = gridDim.x * blockDim.x;
  for (int e = t; e < E; e += stride) {
    atomicAdd(&du[u[e]], 1);
    atomicAdd(&di[it[e]], 1);
  }
}

// --- K3: two single-block exclusive scans, run concurrently (gridDim=2) ------
__global__ void k_scan2(const int* __restrict__ cnt0, int n0, int* __restrict__ off0, int* __restrict__ cur0,
                        const int* __restrict__ cnt1, int n1, int* __restrict__ off1, int* __restrict__ cur1) {
  const int* cnt = blockIdx.x ? cnt1 : cnt0;
  int n          = blockIdx.x ? n1   : n0;
  int* off       = blockIdx.x ? off1 : off0;
  int* cur       = blockIdx.x ? cur1 : cur0;
  __shared__ int wsum_s[16];
  __shared__ int carry_s;
  int t = threadIdx.x, lane = t & 63, wv = t >> 6;
  if (t == 0) carry_s = 0;
  __syncthreads();
  for (int base = 0; base < n; base += 1024 * 8) {
    int v[8];
    int s = 0;
    int i0 = base + t * 8;
#pragma unroll
    for (int k = 0; k < 8; ++k) {
      int idx = i0 + k;
      v[k] = (idx < n) ? cnt[idx] : 0;
      s += v[k];
    }
    int incl = s;
#pragma unroll
    for (int d = 1; d < 64; d <<= 1) {
      int t2 = __shfl_up(incl, d, 64);
      if (lane >= d) incl += t2;
    }
    if (lane == 63) wsum_s[wv] = incl;
    __syncthreads();
    int woff = 0, total = 0;
#pragma unroll
    for (int w = 0; w < 16; ++w) {
      int ws_v = wsum_s[w];
      woff += (w < wv) ? ws_v : 0;
      total += ws_v;
    }
    int excl = carry_s + woff + incl - s;
#pragma unroll
    for (int k = 0; k < 8; ++k) {
      int idx = i0 + k;
      if (idx < n) { off[idx] = excl; cur[idx] = excl; }
      excl += v[k];
    }
    __syncthreads();
    if (t == 0) carry_s += total;
    __syncthreads();
  }
  if (t == 0) off[n] = carry_s;
}

// --- K4: scatter edge ids into CSR lists -------------------------------------
__global__ void k_scatter(const int* __restrict__ u, const int* __restrict__ it, int E,
                          int* __restrict__ ucur, int* __restrict__ icur,
                          int* __restrict__ uedge, int* __restrict__ iedge) {
  int t = blockIdx.x * blockDim.x + threadIdx.x;
  int stride = gridDim.x * blockDim.x;
  for (int e = t; e < E; e += stride) {
    int pu = atomicAdd(&ucur[u[e]], 1);
    uedge[pu] = e;
    int pi = atomicAdd(&icur[it[e]], 1);
    iedge[pi] = e;
  }
}

// --- K5: column sums over items: sum_xi (normalized), sum_vi (raw) -----------
__global__ void k_item_sums(const float* __restrict__ x, const float* __restrict__ inv_norm,
                            float* __restrict__ sum_xi, float* __restrict__ sum_vi) {
  int lane = threadIdx.x; // blockDim.x == 64
  float sx = 0.f, sv = 0.f;
  for (int j = blockIdx.x; j < NI; j += gridDim.x) {
    int r = NU + j;
    float v = x[(size_t)r * DD + lane];
    sv += v;
    sx += v * inv_norm[r];
  }
  atomicAdd(&sum_xi[lane], sx);
  atomicAdd(&sum_vi[lane], sv);
}

// --- K6: fused weighted outer products S (items) and T (users) ----------------
__global__ void k_outer2(const float* __restrict__ x, const float* __restrict__ inv_norm,
                         const int* __restrict__ du,
                         float* __restrict__ Smat, float* __restrict__ Tmat, int gS) {
  bool isT = (int)blockIdx.x >= gS;
  int bfirst = isT ? gS : 0;
  int nb     = isT ? ((int)gridDim.x - gS) : gS;
  int nch    = isT ? (NU / 16) : (NI / 16);
  int row0   = isT ? 0 : NU;
  float* out = isT ? Tmat : Smat;

  __shared__ float rows_s[16 * DD];
  __shared__ float w_s[16];
  int t  = threadIdx.x;
  int a  = t >> 2;
  int c0 = (t & 3) * 16;
  float acc[16];
#pragma unroll
  for (int k = 0; k < 16; ++k) acc[k] = 0.f;

  for (int ch = (int)blockIdx.x - bfirst; ch < nch; ch += nb) {
    int rbase = row0 + ch * 16;
    ((float4*)rows_s)[t] = ((const float4*)(x + (size_t)rbase * DD))[t];
    if (t < 16) {
      int r = rbase + t;
      float w = inv_norm[r];
      if (isT) w /= fmaxf((float)NI - (float)du[r], 1.0f);
      w_s[t] = w;
    }
    __syncthreads();
#pragma unroll
    for (int r = 0; r < 16; ++r) {
      float xa = rows_s[r * DD + a] * w_s[r];
#pragma unroll
      for (int k = 0; k < 16; ++k) acc[k] += xa * rows_s[r * DD + c0 + k];
    }
    __syncthreads();
  }
#pragma unroll
  for (int k = 0; k < 16; ++k) atomicAdd(&out[a * DD + c0 + k], acc[k]);
}

// --- K7: per-user pass — batched metadata preload + 4x unrolled gathers -------
__global__ void k_user(const float* __restrict__ x, const float* __restrict__ inv_norm,
                       const int* __restrict__ uoff, const int* __restrict__ uedge,
                       const int* __restrict__ it, const float* __restrict__ sum_xi,
                       const float* __restrict__ sum_vi, const float* __restrict__ Smat,
                       float* __restrict__ xui, float4* __restrict__ usc,
                       float* __restrict__ out,
                       float* __restrict__ Gx, float* __restrict__ Gv, float* __restrict__ Gb) {
  __shared__ float gx_s[DD], gv_s[DD], gb_s;
  if (threadIdx.x < DD) { gx_s[threadIdx.x] = 0.f; gv_s[threadIdx.x] = 0.f; }
  if (threadIdx.x == 0) gb_s = 0.f;
  __syncthreads();
  int lane = threadIdx.x & 63;
  int wid  = blockIdx.x * (blockDim.x >> 6) + (threadIdx.x >> 6);
  int nw   = gridDim.x * (blockDim.x >> 6);
  float sxl = sum_xi[lane];
  float svl = sum_vi[lane];
  float gx = 0.f, gv = 0.f, gb = 0.f;
  for (int uu = wid; uu < NU; uu += nw) {
    size_t ru = (size_t)uu * DD;
    int beg = uoff[uu], end = uoff[uu + 1];
    float deg = (float)(end - beg);
    float a1 = 1.0f / fmaxf(deg, 1.0f);
    float a2 = 1.0f / fmaxf((float)NI - deg, 1.0f);
    float v_l  = x[ru + lane];
    float xu_l = v_l * inv_norm[uu];
    float A_l = 0.f, sv_l = 0.f, sA = 0.f;
    for (int base = beg; base < end; base += 64) {
      int nb = end - base; if (nb > 64) nb = 64;
      int e_l = 0, ii_l = 0; float inv_l = 0.f;
      if (lane < nb) {
        e_l = uedge[base + lane];
        ii_l = it[e_l];
        inv_l = inv_norm[NU + ii_l];
      }
      for (int k0 = 0; k0 < nb; k0 += 4) {
        bool vB = (k0 + 1 < nb), vC = (k0 + 2 < nb), vD = (k0 + 3 < nb);
        int   iiA = __shfl(ii_l, k0),     iiB = __shfl(ii_l, k0 + 1);
        int   iiC = __shfl(ii_l, k0 + 2), iiD = __shfl(ii_l, k0 + 3);
        float inA = __shfl(inv_l, k0),     inB = __shfl(inv_l, k0 + 1);
        float inC = __shfl(inv_l, k0 + 2), inD = __shfl(inv_l, k0 + 3);
        int   eA  = __shfl(e_l, k0),       eB  = __shfl(e_l, k0 + 1);
        int   eC  = __shfl(e_l, k0 + 2),   eD  = __shfl(e_l, k0 + 3);
        float rA = x[(size_t)(NU + iiA) * DD + lane];
        float rB = vB ? x[(size_t)(NU + iiB) * DD + lane] : 0.f;
        float rC = vC ? x[(size_t)(NU + iiC) * DD + lane] : 0.f;
        float rD = vD ? x[(size_t)(NU + iiD) * DD + lane] : 0.f;
        float dA = wsum(xu_l * rA) * inA;
        float dB = wsum(xu_l * rB) * inB;
        float dC = wsum(xu_l * rC) * inC;
        float dD = wsum(xu_l * rD) * inD;
        if (lane == 0) {
          xui[eA] = dA;
          if (vB) xui[eB] = dB;
          if (vC) xui[eC] = dC;
          if (vD) xui[eD] = dD;
        }
        A_l += dA * rA; A_l += dB * rB; A_l += dC * rC; A_l += dD * rD;
        sv_l += (rA + rB) + (rC + rD);
        sA   += (dA + dB) + (dC + dD);
      }
    }
    float bp = sA * a1;
    float bn = (wsum(xu_l * sxl) - sA) * a2;
    float s1 = (ALPHA_C - bn) * a1;
    float s2 = (bp + ALPHA_C) * a2;
    if (lane == 0) usc[uu] = make_float4(a1, a2, s1, s2);
    float xs0 = 0.f, xs1 = 0.f, xs2 = 0.f, xs3 = 0.f;
#pragma unroll
    for (int a = 0; a < DD; a += 4) {
      xs0 += __shfl(xu_l, a)     * Smat[a * DD + lane];
      xs1 += __shfl(xu_l, a + 1) * Smat[(a + 1) * DD + lane];
      xs2 += __shfl(xu_l, a + 2) * Smat[(a + 2) * DD + lane];
      xs3 += __shfl(xu_l, a + 3) * Smat[(a + 3) * DD + lane];
    }
    float xs = (xs0 + xs1) + (xs2 + xs3);
    float zu = A_l * (a1 - a2) + sv_l * (s1 + s2) + xs * a2 - svl * s2;
    float den = 2.0f * fmaxf(bp - bn + ALPHA_C, EPS_CLAMP);
    out[ru + lane] = zu / den;
    gx += xu_l * a2;
    gv += v_l * s2;
    if (lane == 0) gb += s2;
  }
  atomicAdd(&gx_s[lane], gx);
  atomicAdd(&gv_s[lane], gv);
  if (lane == 0) atomicAdd(&gb_s, gb);
  __syncthreads();
  if (threadIdx.x < DD) {
    atomicAdd(&Gx[threadIdx.x], gx_s[threadIdx.x]);
    atomicAdd(&Gv[threadIdx.x], gv_s[threadIdx.x]);
  }
  if (threadIdx.x == 0) atomicAdd(Gb, gb_s);
}

// --- K8: per-item pass — batched metadata preload + 4x unrolled gathers --------
__global__ void k_item(const float* __restrict__ x, const float* __restrict__ inv_norm,
                       const int* __restrict__ ioff, const int* __restrict__ iedge,
                       const int* __restrict__ u, const float* __restrict__ xui,
                       const float4* __restrict__ usc, const float* __restrict__ Tmat,
                       const float* __restrict__ Gx, const float* __restrict__ Gv,
                       const float* __restrict__ Gb, float* __restrict__ out) {
  int lane = threadIdx.x & 63;
  int wid  = blockIdx.x * (blockDim.x >> 6) + (threadIdx.x >> 6);
  int nw   = gridDim.x * (blockDim.x >> 6);
  float gxl = Gx[lane];
  float gvl = Gv[lane];
  float gb  = *Gb;
  for (int j = wid; j < NI; j += nw) {
    int r = NU + j;
    size_t rr = (size_t)r * DD;
    float xi_l = x[rr + lane] * inv_norm[r];
    int beg = ioff[j], end = ioff[j + 1];
    float W_l = 0.f, q1 = 0.f, q2 = 0.f;
    for (int base = beg; base < end; base += 64) {
      int nb = end - base; if (nb > 64) nb = 64;
      int uu_l = 0; float g_l = 0.f;
      if (lane < nb) {
        int e = iedge[base + lane];
        uu_l = u[e];
        float xv = xui[e];
        float4 c = usc[uu_l];
        g_l = xv * (c.x - c.y) + c.z + c.w;
        q1 += xv * c.x + c.z;
        q2 += xv * c.y - c.w;
      }
      for (int k0 = 0; k0 < nb; k0 += 4) {
        int   uA = __shfl(uu_l, k0),     uB = __shfl(uu_l, k0 + 1);
        int   uC = __shfl(uu_l, k0 + 2), uD = __shfl(uu_l, k0 + 3);
        float gA = __shfl(g_l, k0),      gB = __shfl(g_l, k0 + 1);
        float gC = __shfl(g_l, k0 + 2),  gD = __shfl(g_l, k0 + 3);
        float rA = x[(size_t)uA * DD + lane];
        float rB = x[(size_t)uB * DD + lane];
        float rC = x[(size_t)uC * DD + lane];
        float rD = x[(size_t)uD * DD + lane];
        W_l += gA * rA; W_l += gB * rB; W_l += gC * rC; W_l += gD * rD;
      }
    }
    q1 = wsum(q1);
    q2 = wsum(q2);
    float di1 = q1;
    float di2 = -wsum(xi_l * gxl) + q2 + gb;
    float xt0 = 0.f, xt1 = 0.f, xt2 = 0.f, xt3 = 0.f;
#pragma unroll
    for (int a = 0; a < DD; a += 4) {
      xt0 += __shfl(xi_l, a)     * Tmat[a * DD + lane];
      xt1 += __shfl(xi_l, a + 1) * Tmat[(a + 1) * DD + lane];
      xt2 += __shfl(xi_l, a + 2) * Tmat[(a + 2) * DD + lane];
      xt3 += __shfl(xi_l, a + 3) * Tmat[(a + 3) * DD + lane];
    }
    float xt = (xt0 + xt1) + (xt2 + xt3);
    float zi = W_l + xt - gvl;
    out[rr + lane] = zi / (fmaxf(di1, EPS_CLAMP) + fmaxf(di2, EPS_CLAMP));
  }
}

extern "C" void kernel_launch(void* const* d_in, const int* in_sizes, int n_in,
                              void* d_out, int out_size, void* d_ws, size_t ws_size,
                              hipStream_t stream) {
  const float* x  = (const float*)d_in[0];
  const int*   u  = (const int*)d_in[1];
  const int*   it = (const int*)d_in[2];
  float* out = (float*)d_out;
  const int E = in_sizes[1];
  const int ROWS = NU + NI;

  char* wsb = (char*)d_ws;
  size_t off = 0;
  auto alloc = [&](size_t elems) { void* p = wsb + off; off += elems * 4; return p; };

  // zero-init region (contiguous, first)
  int*   du     = (int*)alloc(100016);
  int*   di     = (int*)alloc(50016);
  float* sum_xi = (float*)alloc(64);
  float* sum_vi = (float*)alloc(64);
  float* Gx     = (float*)alloc(64);
  float* Gv     = (float*)alloc(64);
  float* Gb     = (float*)alloc(16);
  float* Smat   = (float*)alloc(4096);
  float* Tmat   = (float*)alloc(4096);
  size_t zero_bytes = off;

  float*  inv_norm = (float*)alloc(150016);
  int*    uoff     = (int*)alloc(100016);
  int*    ucur     = (int*)alloc(100016);
  int*    ioff     = (int*)alloc(50016);
  int*    icur     = (int*)alloc(50016);
  int*    uedge    = (int*)alloc(1000000);
  int*    iedge    = (int*)alloc(1000000);
  float*  xui      = (float*)alloc(1000000);
  float4* usc      = (float4*)alloc(400000);

  hipMemsetAsync(d_ws, 0, zero_bytes, stream);

  k_norm<<<2048, 256, 0, stream>>>(x, inv_norm, ROWS);
  k_count<<<2048, 256, 0, stream>>>(u, it, du, di, E);
  k_scan2<<<2, 1024, 0, stream>>>(du, NU, uoff, ucur, di, NI, ioff, icur);
  k_scatter<<<2048, 256, 0, stream>>>(u, it, E, ucur, icur, uedge, iedge);
  k_item_sums<<<512, 64, 0, stream>>>(x, inv_norm, sum_xi, sum_vi);
  k_outer2<<<768, 256, 0, stream>>>(x, inv_norm, du, Smat, Tmat, 256);
  k_user<<<2048, 256, 0, stream>>>(x, inv_norm, uoff, uedge, it, sum_xi, sum_vi,
                                   Smat, xui, usc, out, Gx, Gv, Gb);
  k_item<<<2048, 256, 0, stream>>>(x, inv_norm, ioff, iedge, u, xui, usc, Tmat,
                                   Gx, Gv, Gb, out);
}

// Round 5
// 971.533 us; speedup vs baseline: 2.3347x; 1.1129x over previous
//
#include <hip/hip_runtime.h>

#define NU 100000
#define NI 50000
#define DD 64
#define ALPHA_C 1.0f
#define EPS_CLAMP 1e-6f

__device__ __forceinline__ float wsum(float v) {
#pragma unroll
  for (int m = 32; m >= 1; m >>= 1) v += __shfl_xor(v, m, 64);
  return v;
}

// --- K1: per-row inverse norms ---------------------------------------------
__global__ void k_norm(const float* __restrict__ x, float* __restrict__ inv_norm, int rows) {
  int lane = threadIdx.x & 63;
  int wid  = (blockIdx.x * blockDim.x + threadIdx.x) >> 6;
  int nw   = (gridDim.x * blockDim.x) >> 6;
  for (int r = wid; r < rows; r += nw) {
    float v = x[(size_t)r * DD + lane];
    float s = wsum(v * v);
    if (lane == 0) inv_norm[r] = 1.0f / fmaxf(sqrtf(s), 1e-12f);
  }
}

// --- K2: degree counts (int) ------------------------------------------------
__global__ void k_count(const int* __restrict__ u, const int* __restrict__ it,
                        int* __restrict__ du, int* __restrict__ di, int E) {
  int t = blockIdx.x * blockDim.x + threadIdx.x;
  int stride = gridDim.x * blockDim.x;
  for (int e = t; e < E; e += stride) {
    atomicAdd(&du[u[e]], 1);
    atomicAdd(&di[it[e]], 1);
  }
}

// --- K3: two single-block exclusive scans, run concurrently (gridDim=2) ------
__global__ void k_scan2(const int* __restrict__ cnt0, int n0, int* __restrict__ off0, int* __restrict__ cur0,
                        const int* __restrict__ cnt1, int n1, int* __restrict__ off1, int* __restrict__ cur1) {
  const int* cnt = blockIdx.x ? cnt1 : cnt0;
  int n          = blockIdx.x ? n1   : n0;
  int* off       = blockIdx.x ? off1 : off0;
  int* cur       = blockIdx.x ? cur1 : cur0;
  __shared__ int wsum_s[16];
  __shared__ int carry_s;
  int t = threadIdx.x, lane = t & 63, wv = t >> 6;
  if (t == 0) carry_s = 0;
  __syncthreads();
  for (int base = 0; base < n; base += 1024 * 8) {
    int v[8];
    int s = 0;
    int i0 = base + t * 8;
#pragma unroll
    for (int k = 0; k < 8; ++k) {
      int idx = i0 + k;
      v[k] = (idx < n) ? cnt[idx] : 0;
      s += v[k];
    }
    int incl = s;
#pragma unroll
    for (int d = 1; d < 64; d <<= 1) {
      int t2 = __shfl_up(incl, d, 64);
      if (lane >= d) incl += t2;
    }
    if (lane == 63) wsum_s[wv] = incl;
    __syncthreads();
    int woff = 0, total = 0;
#pragma unroll
    for (int w = 0; w < 16; ++w) {
      int ws_v = wsum_s[w];
      woff += (w < wv) ? ws_v : 0;
      total += ws_v;
    }
    int excl = carry_s + woff + incl - s;
#pragma unroll
    for (int k = 0; k < 8; ++k) {
      int idx = i0 + k;
      if (idx < n) { off[idx] = excl; cur[idx] = excl; }
      excl += v[k];
    }
    __syncthreads();
    if (t == 0) carry_s += total;
    __syncthreads();
  }
  if (t == 0) off[n] = carry_s;
}

// --- K4: scatter edge ids into CSR lists -------------------------------------
__global__ void k_scatter(const int* __restrict__ u, const int* __restrict__ it, int E,
                          int* __restrict__ ucur, int* __restrict__ icur,
                          int* __restrict__ uedge, int* __restrict__ iedge) {
  int t = blockIdx.x * blockDim.x + threadIdx.x;
  int stride = gridDim.x * blockDim.x;
  for (int e = t; e < E; e += stride) {
    int pu = atomicAdd(&ucur[u[e]], 1);
    uedge[pu] = e;
    int pi = atomicAdd(&icur[it[e]], 1);
    iedge[pi] = e;
  }
}

// --- K5: column sums over items: sum_xi (normalized), sum_vi (raw) -----------
__global__ void k_item_sums(const float* __restrict__ x, const float* __restrict__ inv_norm,
                            float* __restrict__ sum_xi, float* __restrict__ sum_vi) {
  int lane = threadIdx.x; // blockDim.x == 64
  float sx = 0.f, sv = 0.f;
  for (int j = blockIdx.x; j < NI; j += gridDim.x) {
    int r = NU + j;
    float v = x[(size_t)r * DD + lane];
    sv += v;
    sx += v * inv_norm[r];
  }
  atomicAdd(&sum_xi[lane], sx);
  atomicAdd(&sum_vi[lane], sv);
}

// --- K6: outer products, register-resident rank-1 per wave --------------------
// blocks [0,GS): S over item rows; [GS,GRID): T over user rows.
// wave-private acc[a] = sum_r w_r*row[a]*row[lane]; LDS-atomic block reduce;
// per-block partial -> part (non-atomic). k_redST sums partials.
#define GS_OUTER 64
#define GT_OUTER 128
__global__ void k_outer3(const float* __restrict__ x, const float* __restrict__ inv_norm,
                         const int* __restrict__ du, float* __restrict__ part) {
  __shared__ float red_s[DD * DD];
  bool isT = (int)blockIdx.x >= GS_OUTER;
  int bloc = isT ? (int)blockIdx.x - GS_OUTER : (int)blockIdx.x;
  int nb   = isT ? GT_OUTER : GS_OUTER;
  int nrows = isT ? NU : NI;
  int row0  = isT ? 0 : NU;
  int t = threadIdx.x;
  int lane = t & 63;
  int wv = t >> 6;
  for (int i = t; i < DD * DD; i += 256) red_s[i] = 0.f;
  __syncthreads();

  float acc[DD];
#pragma unroll
  for (int a = 0; a < DD; ++a) acc[a] = 0.f;

  int wid = bloc * 4 + wv;
  int nw  = nb * 4;
  for (int rr = wid; rr < nrows; rr += nw) {
    int r = __builtin_amdgcn_readfirstlane(row0 + rr);
    const float* rowp = x + (size_t)r * DD;
    float w = inv_norm[r];
    if (isT) w /= fmaxf((float)NI - (float)du[r], 1.0f);
    float xb = rowp[lane] * w;
#pragma unroll
    for (int a = 0; a < DD; ++a) acc[a] += rowp[a] * xb;  // rowp[a]: uniform s_load
  }
#pragma unroll
  for (int a = 0; a < DD; ++a) atomicAdd(&red_s[a * DD + lane], acc[a]);
  __syncthreads();
  float4* dst = (float4*)(part + (size_t)blockIdx.x * (DD * DD));
  const float4* src = (const float4*)red_s;
#pragma unroll
  for (int i = 0; i < 4; ++i) dst[t + 256 * i] = src[t + 256 * i];
}

// --- K6b: reduce partials into Smat/Tmat --------------------------------------
__global__ void k_redST(const float* __restrict__ part,
                        float* __restrict__ Smat, float* __restrict__ Tmat) {
  int k = blockIdx.x * blockDim.x + threadIdx.x;  // 0..8191
  if (k < DD * DD) {
    float s = 0.f;
    for (int b = 0; b < GS_OUTER; ++b) s += part[(size_t)b * (DD * DD) + k];
    Smat[k] = s;
  } else {
    int kk = k - DD * DD;
    float s = 0.f;
    for (int b = 0; b < GT_OUTER; ++b) s += part[(size_t)(GS_OUTER + b) * (DD * DD) + kk];
    Tmat[kk] = s;
  }
}

// --- K7: per-user pass — batched metadata preload + 4x unrolled gathers -------
__global__ void k_user(const float* __restrict__ x, const float* __restrict__ inv_norm,
                       const int* __restrict__ uoff, const int* __restrict__ uedge,
                       const int* __restrict__ it, const float* __restrict__ sum_xi,
                       const float* __restrict__ sum_vi, const float* __restrict__ Smat,
                       float* __restrict__ xui, float4* __restrict__ usc,
                       float* __restrict__ out,
                       float* __restrict__ Gx, float* __restrict__ Gv, float* __restrict__ Gb) {
  __shared__ float gx_s[DD], gv_s[DD], gb_s;
  if (threadIdx.x < DD) { gx_s[threadIdx.x] = 0.f; gv_s[threadIdx.x] = 0.f; }
  if (threadIdx.x == 0) gb_s = 0.f;
  __syncthreads();
  int lane = threadIdx.x & 63;
  int wid  = blockIdx.x * (blockDim.x >> 6) + (threadIdx.x >> 6);
  int nw   = gridDim.x * (blockDim.x >> 6);
  float sxl = sum_xi[lane];
  float svl = sum_vi[lane];
  float gx = 0.f, gv = 0.f, gb = 0.f;
  for (int uu = wid; uu < NU; uu += nw) {
    size_t ru = (size_t)uu * DD;
    int beg = uoff[uu], end = uoff[uu + 1];
    float deg = (float)(end - beg);
    float a1 = 1.0f / fmaxf(deg, 1.0f);
    float a2 = 1.0f / fmaxf((float)NI - deg, 1.0f);
    float v_l  = x[ru + lane];
    float xu_l = v_l * inv_norm[uu];
    float A_l = 0.f, sv_l = 0.f, sA = 0.f;
    for (int base = beg; base < end; base += 64) {
      int nb = end - base; if (nb > 64) nb = 64;
      int e_l = 0, ii_l = 0; float inv_l = 0.f;
      if (lane < nb) {
        e_l = uedge[base + lane];
        ii_l = it[e_l];
        inv_l = inv_norm[NU + ii_l];
      }
      for (int k0 = 0; k0 < nb; k0 += 4) {
        bool vB = (k0 + 1 < nb), vC = (k0 + 2 < nb), vD = (k0 + 3 < nb);
        int   iiA = __shfl(ii_l, k0),     iiB = __shfl(ii_l, k0 + 1);
        int   iiC = __shfl(ii_l, k0 + 2), iiD = __shfl(ii_l, k0 + 3);
        float inA = __shfl(inv_l, k0),     inB = __shfl(inv_l, k0 + 1);
        float inC = __shfl(inv_l, k0 + 2), inD = __shfl(inv_l, k0 + 3);
        int   eA  = __shfl(e_l, k0),       eB  = __shfl(e_l, k0 + 1);
        int   eC  = __shfl(e_l, k0 + 2),   eD  = __shfl(e_l, k0 + 3);
        float rA = x[(size_t)(NU + iiA) * DD + lane];
        float rB = vB ? x[(size_t)(NU + iiB) * DD + lane] : 0.f;
        float rC = vC ? x[(size_t)(NU + iiC) * DD + lane] : 0.f;
        float rD = vD ? x[(size_t)(NU + iiD) * DD + lane] : 0.f;
        float dA = wsum(xu_l * rA) * inA;
        float dB = wsum(xu_l * rB) * inB;
        float dC = wsum(xu_l * rC) * inC;
        float dD = wsum(xu_l * rD) * inD;
        if (lane == 0) {
          xui[eA] = dA;
          if (vB) xui[eB] = dB;
          if (vC) xui[eC] = dC;
          if (vD) xui[eD] = dD;
        }
        A_l += dA * rA; A_l += dB * rB; A_l += dC * rC; A_l += dD * rD;
        sv_l += (rA + rB) + (rC + rD);
        sA   += (dA + dB) + (dC + dD);
      }
    }
    float bp = sA * a1;
    float bn = (wsum(xu_l * sxl) - sA) * a2;
    float s1 = (ALPHA_C - bn) * a1;
    float s2 = (bp + ALPHA_C) * a2;
    if (lane == 0) usc[uu] = make_float4(a1, a2, s1, s2);
    float xs0 = 0.f, xs1 = 0.f, xs2 = 0.f, xs3 = 0.f;
#pragma unroll
    for (int a = 0; a < DD; a += 4) {
      xs0 += __shfl(xu_l, a)     * Smat[a * DD + lane];
      xs1 += __shfl(xu_l, a + 1) * Smat[(a + 1) * DD + lane];
      xs2 += __shfl(xu_l, a + 2) * Smat[(a + 2) * DD + lane];
      xs3 += __shfl(xu_l, a + 3) * Smat[(a + 3) * DD + lane];
    }
    float xs = (xs0 + xs1) + (xs2 + xs3);
    float zu = A_l * (a1 - a2) + sv_l * (s1 + s2) + xs * a2 - svl * s2;
    float den = 2.0f * fmaxf(bp - bn + ALPHA_C, EPS_CLAMP);
    out[ru + lane] = zu / den;
    gx += xu_l * a2;
    gv += v_l * s2;
    if (lane == 0) gb += s2;
  }
  atomicAdd(&gx_s[lane], gx);
  atomicAdd(&gv_s[lane], gv);
  if (lane == 0) atomicAdd(&gb_s, gb);
  __syncthreads();
  if (threadIdx.x < DD) {
    atomicAdd(&Gx[threadIdx.x], gx_s[threadIdx.x]);
    atomicAdd(&Gv[threadIdx.x], gv_s[threadIdx.x]);
  }
  if (threadIdx.x == 0) atomicAdd(Gb, gb_s);
}

// --- K8: per-item pass — batched metadata preload + 4x unrolled gathers --------
__global__ void k_item(const float* __restrict__ x, const float* __restrict__ inv_norm,
                       const int* __restrict__ ioff, const int* __restrict__ iedge,
                       const int* __restrict__ u, const float* __restrict__ xui,
                       const float4* __restrict__ usc, const float* __restrict__ Tmat,
                       const float* __restrict__ Gx, const float* __restrict__ Gv,
                       const float* __restrict__ Gb, float* __restrict__ out) {
  int lane = threadIdx.x & 63;
  int wid  = blockIdx.x * (blockDim.x >> 6) + (threadIdx.x >> 6);
  int nw   = gridDim.x * (blockDim.x >> 6);
  float gxl = Gx[lane];
  float gvl = Gv[lane];
  float gb  = *Gb;
  for (int j = wid; j < NI; j += nw) {
    int r = NU + j;
    size_t rr = (size_t)r * DD;
    float xi_l = x[rr + lane] * inv_norm[r];
    int beg = ioff[j], end = ioff[j + 1];
    float W_l = 0.f, q1 = 0.f, q2 = 0.f;
    for (int base = beg; base < end; base += 64) {
      int nb = end - base; if (nb > 64) nb = 64;
      int uu_l = 0; float g_l = 0.f;
      if (lane < nb) {
        int e = iedge[base + lane];
        uu_l = u[e];
        float xv = xui[e];
        float4 c = usc[uu_l];
        g_l = xv * (c.x - c.y) + c.z + c.w;
        q1 += xv * c.x + c.z;
        q2 += xv * c.y - c.w;
      }
      for (int k0 = 0; k0 < nb; k0 += 4) {
        int   uA = __shfl(uu_l, k0),     uB = __shfl(uu_l, k0 + 1);
        int   uC = __shfl(uu_l, k0 + 2), uD = __shfl(uu_l, k0 + 3);
        float gA = __shfl(g_l, k0),      gB = __shfl(g_l, k0 + 1);
        float gC = __shfl(g_l, k0 + 2),  gD = __shfl(g_l, k0 + 3);
        float rA = x[(size_t)uA * DD + lane];
        float rB = x[(size_t)uB * DD + lane];
        float rC = x[(size_t)uC * DD + lane];
        float rD = x[(size_t)uD * DD + lane];
        W_l += gA * rA; W_l += gB * rB; W_l += gC * rC; W_l += gD * rD;
      }
    }
    q1 = wsum(q1);
    q2 = wsum(q2);
    float di1 = q1;
    float di2 = -wsum(xi_l * gxl) + q2 + gb;
    float xt0 = 0.f, xt1 = 0.f, xt2 = 0.f, xt3 = 0.f;
#pragma unroll
    for (int a = 0; a < DD; a += 4) {
      xt0 += __shfl(xi_l, a)     * Tmat[a * DD + lane];
      xt1 += __shfl(xi_l, a + 1) * Tmat[(a + 1) * DD + lane];
      xt2 += __shfl(xi_l, a + 2) * Tmat[(a + 2) * DD + lane];
      xt3 += __shfl(xi_l, a + 3) * Tmat[(a + 3) * DD + lane];
    }
    float xt = (xt0 + xt1) + (xt2 + xt3);
    float zi = W_l + xt - gvl;
    out[rr + lane] = zi / (fmaxf(di1, EPS_CLAMP) + fmaxf(di2, EPS_CLAMP));
  }
}

extern "C" void kernel_launch(void* const* d_in, const int* in_sizes, int n_in,
                              void* d_out, int out_size, void* d_ws, size_t ws_size,
                              hipStream_t stream) {
  const float* x  = (const float*)d_in[0];
  const int*   u  = (const int*)d_in[1];
  const int*   it = (const int*)d_in[2];
  float* out = (float*)d_out;
  const int E = in_sizes[1];
  const int ROWS = NU + NI;

  char* wsb = (char*)d_ws;
  size_t off = 0;
  auto alloc = [&](size_t elems) { void* p = wsb + off; off += elems * 4; return p; };

  // zero-init region (contiguous, first)
  int*   du     = (int*)alloc(100016);
  int*   di     = (int*)alloc(50016);
  float* sum_xi = (float*)alloc(64);
  float* sum_vi = (float*)alloc(64);
  float* Gx     = (float*)alloc(64);
  float* Gv     = (float*)alloc(64);
  float* Gb     = (float*)alloc(16);
  size_t zero_bytes = off;

  float* Smat   = (float*)alloc(4096);
  float* Tmat   = (float*)alloc(4096);
  float* part   = (float*)alloc((size_t)(GS_OUTER + GT_OUTER) * 4096);
  float*  inv_norm = (float*)alloc(150016);
  int*    uoff     = (int*)alloc(100016);
  int*    ucur     = (int*)alloc(100016);
  int*    ioff     = (int*)alloc(50016);
  int*    icur     = (int*)alloc(50016);
  int*    uedge    = (int*)alloc(1000000);
  int*    iedge    = (int*)alloc(1000000);
  float*  xui      = (float*)alloc(1000000);
  float4* usc      = (float4*)alloc(400000);

  hipMemsetAsync(d_ws, 0, zero_bytes, stream);

  k_norm<<<2048, 256, 0, stream>>>(x, inv_norm, ROWS);
  k_count<<<2048, 256, 0, stream>>>(u, it, du, di, E);
  k_scan2<<<2, 1024, 0, stream>>>(du, NU, uoff, ucur, di, NI, ioff, icur);
  k_scatter<<<2048, 256, 0, stream>>>(u, it, E, ucur, icur, uedge, iedge);
  k_item_sums<<<512, 64, 0, stream>>>(x, inv_norm, sum_xi, sum_vi);
  k_outer3<<<GS_OUTER + GT_OUTER, 256, 0, stream>>>(x, inv_norm, du, part);
  k_redST<<<32, 256, 0, stream>>>(part, Smat, Tmat);
  k_user<<<2048, 256, 0, stream>>>(x, inv_norm, uoff, uedge, it, sum_xi, sum_vi,
                                   Smat, xui, usc, out, Gx, Gv, Gb);
  k_item<<<2048, 256, 0, stream>>>(x, inv_norm, ioff, iedge, u, xui, usc, Tmat,
                                   Gx, Gv, Gb, out);
}

// Round 6
// 937.020 us; speedup vs baseline: 2.4207x; 1.0368x over previous
//
#include <hip/hip_runtime.h>

#define NU 100000
#define NI 50000
#define DD 64
#define ALPHA_C 1.0f
#define EPS_CLAMP 1e-6f

__device__ __forceinline__ float wsum(float v) {
#pragma unroll
  for (int m = 32; m >= 1; m >>= 1) v += __shfl_xor(v, m, 64);
  return v;
}

// --- K1: per-row inverse norms + item column sums (fused) --------------------
__global__ void k_norm_sums(const float* __restrict__ x, float* __restrict__ inv_norm,
                            float* __restrict__ sum_xi, float* __restrict__ sum_vi) {
  __shared__ float sx_s[DD], sv_s[DD];
  if (threadIdx.x < DD) { sx_s[threadIdx.x] = 0.f; sv_s[threadIdx.x] = 0.f; }
  __syncthreads();
  int lane = threadIdx.x & 63;
  int wid  = blockIdx.x * 4 + (threadIdx.x >> 6);
  int nw   = gridDim.x * 4;
  float sx = 0.f, sv = 0.f;
  for (int r = wid; r < NU + NI; r += nw) {
    float v = x[(size_t)r * DD + lane];
    float s = wsum(v * v);
    float inv = 1.0f / fmaxf(sqrtf(s), 1e-12f);
    if (lane == 0) inv_norm[r] = inv;
    if (r >= NU) { sv += v; sx += v * inv; }
  }
  atomicAdd(&sx_s[lane], sx);
  atomicAdd(&sv_s[lane], sv);
  __syncthreads();
  if (threadIdx.x < DD) {
    atomicAdd(&sum_xi[threadIdx.x], sx_s[threadIdx.x]);
    atomicAdd(&sum_vi[threadIdx.x], sv_s[threadIdx.x]);
  }
}

// --- K2: degree counts (int) ------------------------------------------------
__global__ void k_count(const int* __restrict__ u, const int* __restrict__ it,
                        int* __restrict__ du, int* __restrict__ di, int E) {
  int t = blockIdx.x * blockDim.x + threadIdx.x;
  int stride = gridDim.x * blockDim.x;
  for (int e = t; e < E; e += stride) {
    atomicAdd(&du[u[e]], 1);
    atomicAdd(&di[it[e]], 1);
  }
}

// --- K3: two single-block exclusive scans, run concurrently (gridDim=2) ------
__global__ void k_scan2(const int* __restrict__ cnt0, int n0, int* __restrict__ off0, int* __restrict__ cur0,
                        const int* __restrict__ cnt1, int n1, int* __restrict__ off1, int* __restrict__ cur1) {
  const int* cnt = blockIdx.x ? cnt1 : cnt0;
  int n          = blockIdx.x ? n1   : n0;
  int* off       = blockIdx.x ? off1 : off0;
  int* cur       = blockIdx.x ? cur1 : cur0;
  __shared__ int wsum_s[16];
  __shared__ int carry_s;
  int t = threadIdx.x, lane = t & 63, wv = t >> 6;
  if (t == 0) carry_s = 0;
  __syncthreads();
  for (int base = 0; base < n; base += 1024 * 8) {
    int v[8];
    int s = 0;
    int i0 = base + t * 8;
#pragma unroll
    for (int k = 0; k < 8; ++k) {
      int idx = i0 + k;
      v[k] = (idx < n) ? cnt[idx] : 0;
      s += v[k];
    }
    int incl = s;
#pragma unroll
    for (int d = 1; d < 64; d <<= 1) {
      int t2 = __shfl_up(incl, d, 64);
      if (lane >= d) incl += t2;
    }
    if (lane == 63) wsum_s[wv] = incl;
    __syncthreads();
    int woff = 0, total = 0;
#pragma unroll
    for (int w = 0; w < 16; ++w) {
      int ws_v = wsum_s[w];
      woff += (w < wv) ? ws_v : 0;
      total += ws_v;
    }
    int excl = carry_s + woff + incl - s;
#pragma unroll
    for (int k = 0; k < 8; ++k) {
      int idx = i0 + k;
      if (idx < n) { off[idx] = excl; cur[idx] = excl; }
      excl += v[k];
    }
    __syncthreads();
    if (t == 0) carry_s += total;
    __syncthreads();
  }
  if (t == 0) off[n] = carry_s;
}

// --- K4: scatter edges into CSR lists with embedded metadata ------------------
// uev[pu] = (item ii, item-CSR position pi); iuu[pi] = user uu.
__global__ void k_scatter2(const int* __restrict__ u, const int* __restrict__ it, int E,
                           int* __restrict__ ucur, int* __restrict__ icur,
                           int2* __restrict__ uev, int* __restrict__ iuu) {
  int t = blockIdx.x * blockDim.x + threadIdx.x;
  int stride = gridDim.x * blockDim.x;
  for (int e = t; e < E; e += stride) {
    int uu = u[e], ii = it[e];
    int pu = atomicAdd(&ucur[uu], 1);
    int pi = atomicAdd(&icur[ii], 1);
    uev[pu] = make_int2(ii, pi);
    iuu[pi] = uu;
  }
}

// --- K6: outer products, register-resident rank-1 per wave --------------------
#define GS_OUTER 64
#define GT_OUTER 128
__global__ void k_outer3(const float* __restrict__ x, const float* __restrict__ inv_norm,
                         const int* __restrict__ du, float* __restrict__ part) {
  __shared__ float red_s[DD * DD];
  bool isT = (int)blockIdx.x >= GS_OUTER;
  int bloc = isT ? (int)blockIdx.x - GS_OUTER : (int)blockIdx.x;
  int nb   = isT ? GT_OUTER : GS_OUTER;
  int nrows = isT ? NU : NI;
  int row0  = isT ? 0 : NU;
  int t = threadIdx.x;
  int lane = t & 63;
  int wv = t >> 6;
  for (int i = t; i < DD * DD; i += 256) red_s[i] = 0.f;
  __syncthreads();

  float acc[DD];
#pragma unroll
  for (int a = 0; a < DD; ++a) acc[a] = 0.f;

  int wid = bloc * 4 + wv;
  int nw  = nb * 4;
  for (int rr = wid; rr < nrows; rr += nw) {
    int r = __builtin_amdgcn_readfirstlane(row0 + rr);
    const float* rowp = x + (size_t)r * DD;
    float w = inv_norm[r];
    if (isT) w /= fmaxf((float)NI - (float)du[r], 1.0f);
    float xb = rowp[lane] * w;
#pragma unroll
    for (int a = 0; a < DD; ++a) acc[a] += rowp[a] * xb;
  }
#pragma unroll
  for (int a = 0; a < DD; ++a) atomicAdd(&red_s[a * DD + lane], acc[a]);
  __syncthreads();
  float4* dst = (float4*)(part + (size_t)blockIdx.x * (DD * DD));
  const float4* src = (const float4*)red_s;
#pragma unroll
  for (int i = 0; i < 4; ++i) dst[t + 256 * i] = src[t + 256 * i];
}

// --- K6b: reduce partials into Smat/Tmat --------------------------------------
__global__ void k_redST(const float* __restrict__ part,
                        float* __restrict__ Smat, float* __restrict__ Tmat) {
  int k = blockIdx.x * blockDim.x + threadIdx.x;  // 0..8191
  if (k < DD * DD) {
    float s = 0.f;
    for (int b = 0; b < GS_OUTER; ++b) s += part[(size_t)b * (DD * DD) + k];
    Smat[k] = s;
  } else {
    int kk = k - DD * DD;
    float s = 0.f;
    for (int b = 0; b < GT_OUTER; ++b) s += part[(size_t)(GS_OUTER + b) * (DD * DD) + kk];
    Tmat[kk] = s;
  }
}

// --- K7: per-user pass — linear metadata, 8x unrolled gathers, emits te -------
__global__ void k_user2(const float* __restrict__ x, const float* __restrict__ inv_norm,
                        const int* __restrict__ uoff, const int2* __restrict__ uev,
                        const float* __restrict__ sum_xi, const float* __restrict__ sum_vi,
                        const float* __restrict__ Smat,
                        float2* __restrict__ te, float* __restrict__ out,
                        float* __restrict__ Gx, float* __restrict__ Gv, float* __restrict__ Gb) {
  __shared__ float gx_s[DD], gv_s[DD], gb_s;
  if (threadIdx.x < DD) { gx_s[threadIdx.x] = 0.f; gv_s[threadIdx.x] = 0.f; }
  if (threadIdx.x == 0) gb_s = 0.f;
  __syncthreads();
  int lane = threadIdx.x & 63;
  int wid  = blockIdx.x * (blockDim.x >> 6) + (threadIdx.x >> 6);
  int nw   = gridDim.x * (blockDim.x >> 6);
  float sxl = sum_xi[lane];
  float svl = sum_vi[lane];
  float* tex = (float*)te;
  float gx = 0.f, gv = 0.f, gb = 0.f;
  for (int uu = wid; uu < NU; uu += nw) {
    size_t ru = (size_t)uu * DD;
    int beg = uoff[uu], end2 = uoff[uu + 1];
    int deg = end2 - beg;
    float a1 = 1.0f / fmaxf((float)deg, 1.0f);
    float a2 = 1.0f / fmaxf((float)(NI - deg), 1.0f);
    float v_l  = x[ru + lane];
    float xu_l = v_l * inv_norm[uu];
    bool multi = deg > 64;
    float A_l = 0.f, sv_l = 0.f, sA = 0.f;
    int2 mkeep = make_int2(0, 0);
    float dkeep = 0.f;
    for (int base = beg; base < end2; base += 64) {
      int nb = end2 - base; if (nb > 64) nb = 64;
      int2 m = make_int2(0, 0);
      float inv_l = 0.f;
      if (lane < nb) {
        m = uev[base + lane];
        inv_l = inv_norm[NU + m.x];
      }
      float dm = 0.f;
      for (int k0 = 0; k0 < nb; k0 += 8) {
        float r[8];
#pragma unroll
        for (int j = 0; j < 8; ++j) {
          int ii = __shfl(m.x, k0 + j);
          r[j] = (k0 + j < nb) ? x[(size_t)(NU + ii) * DD + lane] : 0.f;
        }
#pragma unroll
        for (int j = 0; j < 8; ++j) {
          float inj = __shfl(inv_l, k0 + j);
          float d = wsum(xu_l * r[j]) * inj;
          if (lane == k0 + j) dm = d;
          A_l  += d * r[j];
          sv_l += r[j];
          sA   += d;
        }
      }
      if (multi && lane < nb) tex[2 * (size_t)m.y] = dm;  // stash raw dot
      mkeep = m; dkeep = dm;
    }
    float bp = sA * a1;
    float bn = (wsum(xu_l * sxl) - sA) * a2;
    float s1 = (ALPHA_C - bn) * a1;
    float s2 = (bp + ALPHA_C) * a2;
    if (!multi) {
      if (lane < deg) te[mkeep.y] = make_float2(dkeep * a1 + s1, dkeep * a2 - s2);
    } else {
      for (int k = beg + lane; k < end2; k += 64) {
        int2 m2 = uev[k];
        float dv = tex[2 * (size_t)m2.y];  // same lane wrote it: per-thread RAW order
        te[m2.y] = make_float2(dv * a1 + s1, dv * a2 - s2);
      }
    }
    float xs0 = 0.f, xs1 = 0.f, xs2 = 0.f, xs3 = 0.f;
#pragma unroll
    for (int a = 0; a < DD; a += 4) {
      xs0 += __shfl(xu_l, a)     * Smat[a * DD + lane];
      xs1 += __shfl(xu_l, a + 1) * Smat[(a + 1) * DD + lane];
      xs2 += __shfl(xu_l, a + 2) * Smat[(a + 2) * DD + lane];
      xs3 += __shfl(xu_l, a + 3) * Smat[(a + 3) * DD + lane];
    }
    float xs = (xs0 + xs1) + (xs2 + xs3);
    float zu = A_l * (a1 - a2) + sv_l * (s1 + s2) + xs * a2 - svl * s2;
    float den = 2.0f * fmaxf(bp - bn + ALPHA_C, EPS_CLAMP);
    out[ru + lane] = zu / den;
    gx += xu_l * a2;
    gv += v_l * s2;
    if (lane == 0) gb += s2;
  }
  atomicAdd(&gx_s[lane], gx);
  atomicAdd(&gv_s[lane], gv);
  if (lane == 0) atomicAdd(&gb_s, gb);
  __syncthreads();
  if (threadIdx.x < DD) {
    atomicAdd(&Gx[threadIdx.x], gx_s[threadIdx.x]);
    atomicAdd(&Gv[threadIdx.x], gv_s[threadIdx.x]);
  }
  if (threadIdx.x == 0) atomicAdd(Gb, gb_s);
}

// --- K8: per-item pass — fully linear metadata, 8x unrolled gathers ------------
__global__ void k_item2(const float* __restrict__ x, const float* __restrict__ inv_norm,
                        const int* __restrict__ ioff, const int* __restrict__ iuu,
                        const float2* __restrict__ te, const float* __restrict__ Tmat,
                        const float* __restrict__ Gx, const float* __restrict__ Gv,
                        const float* __restrict__ Gb, float* __restrict__ out) {
  int lane = threadIdx.x & 63;
  int wid  = blockIdx.x * (blockDim.x >> 6) + (threadIdx.x >> 6);
  int nw   = gridDim.x * (blockDim.x >> 6);
  float gxl = Gx[lane];
  float gvl = Gv[lane];
  float gb  = *Gb;
  for (int j = wid; j < NI; j += nw) {
    int r = NU + j;
    size_t rr = (size_t)r * DD;
    float xi_l = x[rr + lane] * inv_norm[r];
    int beg = ioff[j], end2 = ioff[j + 1];
    float W_l = 0.f, q1 = 0.f, q2 = 0.f;
    for (int base = beg; base < end2; base += 64) {
      int nb = end2 - base; if (nb > 64) nb = 64;
      int uu_l = 0;
      float2 t = make_float2(0.f, 0.f);
      if (lane < nb) {
        uu_l = iuu[base + lane];
        t = te[base + lane];
        q1 += t.x;
        q2 += t.y;
      }
      float gl = t.x - t.y;
      for (int k0 = 0; k0 < nb; k0 += 8) {
#pragma unroll
        for (int jj = 0; jj < 8; ++jj) {
          int   uA = __shfl(uu_l, k0 + jj);
          float gA = __shfl(gl, k0 + jj);
          float rA = (k0 + jj < nb) ? x[(size_t)uA * DD + lane] : 0.f;
          W_l += gA * rA;
        }
      }
    }
    q1 = wsum(q1);
    q2 = wsum(q2);
    float di1 = q1;
    float di2 = -wsum(xi_l * gxl) + q2 + gb;
    float xt0 = 0.f, xt1 = 0.f, xt2 = 0.f, xt3 = 0.f;
#pragma unroll
    for (int a = 0; a < DD; a += 4) {
      xt0 += __shfl(xi_l, a)     * Tmat[a * DD + lane];
      xt1 += __shfl(xi_l, a + 1) * Tmat[(a + 1) * DD + lane];
      xt2 += __shfl(xi_l, a + 2) * Tmat[(a + 2) * DD + lane];
      xt3 += __shfl(xi_l, a + 3) * Tmat[(a + 3) * DD + lane];
    }
    float xt = (xt0 + xt1) + (xt2 + xt3);
    float zi = W_l + xt - gvl;
    out[rr + lane] = zi / (fmaxf(di1, EPS_CLAMP) + fmaxf(di2, EPS_CLAMP));
  }
}

extern "C" void kernel_launch(void* const* d_in, const int* in_sizes, int n_in,
                              void* d_out, int out_size, void* d_ws, size_t ws_size,
                              hipStream_t stream) {
  const float* x  = (const float*)d_in[0];
  const int*   u  = (const int*)d_in[1];
  const int*   it = (const int*)d_in[2];
  float* out = (float*)d_out;
  const int E = in_sizes[1];

  char* wsb = (char*)d_ws;
  size_t off = 0;
  auto alloc = [&](size_t elems) { void* p = wsb + off; off += elems * 4; return p; };

  // zero-init region (contiguous, first)
  int*   du     = (int*)alloc(100016);
  int*   di     = (int*)alloc(50016);
  float* sum_xi = (float*)alloc(64);
  float* sum_vi = (float*)alloc(64);
  float* Gx     = (float*)alloc(64);
  float* Gv     = (float*)alloc(64);
  float* Gb     = (float*)alloc(16);
  size_t zero_bytes = off;

  float* Smat   = (float*)alloc(4096);
  float* Tmat   = (float*)alloc(4096);
  float* part   = (float*)alloc((size_t)(GS_OUTER + GT_OUTER) * 4096);
  float*  inv_norm = (float*)alloc(150016);
  int*    uoff     = (int*)alloc(100016);
  int*    ucur     = (int*)alloc(100016);
  int*    ioff     = (int*)alloc(50016);
  int*    icur     = (int*)alloc(50016);
  int2*   uev      = (int2*)alloc(2000000);
  int*    iuu      = (int*)alloc(1000000);
  float2* te       = (float2*)alloc(2000000);

  hipMemsetAsync(d_ws, 0, zero_bytes, stream);

  k_norm_sums<<<1024, 256, 0, stream>>>(x, inv_norm, sum_xi, sum_vi);
  k_count<<<2048, 256, 0, stream>>>(u, it, du, di, E);
  k_scan2<<<2, 1024, 0, stream>>>(du, NU, uoff, ucur, di, NI, ioff, icur);
  k_scatter2<<<2048, 256, 0, stream>>>(u, it, E, ucur, icur, uev, iuu);
  k_outer3<<<GS_OUTER + GT_OUTER, 256, 0, stream>>>(x, inv_norm, du, part);
  k_redST<<<32, 256, 0, stream>>>(part, Smat, Tmat);
  k_user2<<<2048, 256, 0, stream>>>(x, inv_norm, uoff, uev, sum_xi, sum_vi,
                                    Smat, te, out, Gx, Gv, Gb);
  k_item2<<<2048, 256, 0, stream>>>(x, inv_norm, ioff, iuu, te, Tmat,
                                    Gx, Gv, Gb, out);
}

// Round 7
// 909.789 us; speedup vs baseline: 2.4931x; 1.0299x over previous
//
#include <hip/hip_runtime.h>

#define NU 100000
#define NI 50000
#define DD 64
#define ALPHA_C 1.0f
#define EPS_CLAMP 1e-6f

__device__ __forceinline__ float rsum16(float v) {
  v += __shfl_xor(v, 1, 64);
  v += __shfl_xor(v, 2, 64);
  v += __shfl_xor(v, 4, 64);
  v += __shfl_xor(v, 8, 64);
  return v;
}
__device__ __forceinline__ float xgrp2(float v) {
  v += __shfl_xor(v, 16, 64);
  v += __shfl_xor(v, 32, 64);
  return v;
}
__device__ __forceinline__ float wsum(float v) { return xgrp2(rsum16(v)); }

// --- K1: norms + item column sums, float4 layout (4 rows per wave-iter) ------
__global__ void k_norm_sums(const float* __restrict__ x, float* __restrict__ inv_norm,
                            float* __restrict__ sum_xi, float* __restrict__ sum_vi) {
  __shared__ float sx_s[DD], sv_s[DD];
  if (threadIdx.x < DD) { sx_s[threadIdx.x] = 0.f; sv_s[threadIdx.x] = 0.f; }
  __syncthreads();
  int lane = threadIdx.x & 63;
  int g = lane >> 4, c = lane & 15;
  int wid = blockIdx.x * 4 + (threadIdx.x >> 6);
  int nw  = gridDim.x * 4;
  float sx0=0,sx1=0,sx2=0,sx3=0, sv0=0,sv1=0,sv2=0,sv3=0;
  for (int rb = wid * 4; rb < NU + NI; rb += nw * 4) {
    int r = rb + g;
    const float4 v4 = *(const float4*)(x + (size_t)r * DD + 4 * c);
    float p = v4.x*v4.x + v4.y*v4.y + v4.z*v4.z + v4.w*v4.w;
    p = rsum16(p);
    float inv = 1.0f / fmaxf(sqrtf(p), 1e-12f);
    if (c == 0) inv_norm[r] = inv;
    float fi = (r >= NU) ? 1.f : 0.f;
    float fx = fi * inv;
    sv0 += fi*v4.x; sv1 += fi*v4.y; sv2 += fi*v4.z; sv3 += fi*v4.w;
    sx0 += fx*v4.x; sx1 += fx*v4.y; sx2 += fx*v4.z; sx3 += fx*v4.w;
  }
  atomicAdd(&sx_s[4*c+0], sx0); atomicAdd(&sx_s[4*c+1], sx1);
  atomicAdd(&sx_s[4*c+2], sx2); atomicAdd(&sx_s[4*c+3], sx3);
  atomicAdd(&sv_s[4*c+0], sv0); atomicAdd(&sv_s[4*c+1], sv1);
  atomicAdd(&sv_s[4*c+2], sv2); atomicAdd(&sv_s[4*c+3], sv3);
  __syncthreads();
  if (threadIdx.x < DD) {
    atomicAdd(&sum_xi[threadIdx.x], sx_s[threadIdx.x]);
    atomicAdd(&sum_vi[threadIdx.x], sv_s[threadIdx.x]);
  }
}

// --- K2: degree counts -------------------------------------------------------
__global__ void k_count(const int* __restrict__ u, const int* __restrict__ it,
                        int* __restrict__ du, int* __restrict__ di, int E) {
  int t = blockIdx.x * blockDim.x + threadIdx.x;
  int stride = gridDim.x * blockDim.x;
  for (int e = t; e < E; e += stride) {
    atomicAdd(&du[u[e]], 1);
    atomicAdd(&di[it[e]], 1);
  }
}

// --- K3: two single-block exclusive scans ------------------------------------
__global__ void k_scan2(const int* __restrict__ cnt0, int n0, int* __restrict__ off0, int* __restrict__ cur0,
                        const int* __restrict__ cnt1, int n1, int* __restrict__ off1, int* __restrict__ cur1) {
  const int* cnt = blockIdx.x ? cnt1 : cnt0;
  int n          = blockIdx.x ? n1   : n0;
  int* off       = blockIdx.x ? off1 : off0;
  int* cur       = blockIdx.x ? cur1 : cur0;
  __shared__ int wsum_s[16];
  __shared__ int carry_s;
  int t = threadIdx.x, lane = t & 63, wv = t >> 6;
  if (t == 0) carry_s = 0;
  __syncthreads();
  for (int base = 0; base < n; base += 1024 * 8) {
    int v[8];
    int s = 0;
    int i0 = base + t * 8;
#pragma unroll
    for (int k = 0; k < 8; ++k) {
      int idx = i0 + k;
      v[k] = (idx < n) ? cnt[idx] : 0;
      s += v[k];
    }
    int incl = s;
#pragma unroll
    for (int d = 1; d < 64; d <<= 1) {
      int t2 = __shfl_up(incl, d, 64);
      if (lane >= d) incl += t2;
    }
    if (lane == 63) wsum_s[wv] = incl;
    __syncthreads();
    int woff = 0, total = 0;
#pragma unroll
    for (int w = 0; w < 16; ++w) {
      int ws_v = wsum_s[w];
      woff += (w < wv) ? ws_v : 0;
      total += ws_v;
    }
    int excl = carry_s + woff + incl - s;
#pragma unroll
    for (int k = 0; k < 8; ++k) {
      int idx = i0 + k;
      if (idx < n) { off[idx] = excl; cur[idx] = excl; }
      excl += v[k];
    }
    __syncthreads();
    if (t == 0) carry_s += total;
    __syncthreads();
  }
  if (t == 0) off[n] = carry_s;
}

// --- K4: scatter edges with embedded metadata ---------------------------------
__global__ void k_scatter2(const int* __restrict__ u, const int* __restrict__ it, int E,
                           int* __restrict__ ucur, int* __restrict__ icur,
                           int2* __restrict__ uev, int* __restrict__ iuu) {
  int t = blockIdx.x * blockDim.x + threadIdx.x;
  int stride = gridDim.x * blockDim.x;
  for (int e = t; e < E; e += stride) {
    int uu = u[e], ii = it[e];
    int pu = atomicAdd(&ucur[uu], 1);
    int pi = atomicAdd(&icur[ii], 1);
    uev[pu] = make_int2(ii, pi);
    iuu[pi] = uu;
  }
}

// --- K6: outer products, register-resident rank-1 per wave --------------------
#define GS_OUTER 64
#define GT_OUTER 128
__global__ void k_outer3(const float* __restrict__ x, const float* __restrict__ inv_norm,
                         const int* __restrict__ du, float* __restrict__ part) {
  __shared__ float red_s[DD * DD];
  bool isT = (int)blockIdx.x >= GS_OUTER;
  int bloc = isT ? (int)blockIdx.x - GS_OUTER : (int)blockIdx.x;
  int nb   = isT ? GT_OUTER : GS_OUTER;
  int nrows = isT ? NU : NI;
  int row0  = isT ? 0 : NU;
  int t = threadIdx.x;
  int lane = t & 63;
  int wv = t >> 6;
  for (int i = t; i < DD * DD; i += 256) red_s[i] = 0.f;
  __syncthreads();

  float acc[DD];
#pragma unroll
  for (int a = 0; a < DD; ++a) acc[a] = 0.f;

  int wid = bloc * 4 + wv;
  int nw  = nb * 4;
  for (int rr = wid; rr < nrows; rr += nw) {
    int r = __builtin_amdgcn_readfirstlane(row0 + rr);
    const float* rowp = x + (size_t)r * DD;
    float w = inv_norm[r];
    if (isT) w /= fmaxf((float)NI - (float)du[r], 1.0f);
    float xb = rowp[lane] * w;
#pragma unroll
    for (int a = 0; a < DD; ++a) acc[a] += rowp[a] * xb;
  }
#pragma unroll
  for (int a = 0; a < DD; ++a) atomicAdd(&red_s[a * DD + lane], acc[a]);
  __syncthreads();
  float4* dst = (float4*)(part + (size_t)blockIdx.x * (DD * DD));
  const float4* src = (const float4*)red_s;
#pragma unroll
  for (int i = 0; i < 4; ++i) dst[t + 256 * i] = src[t + 256 * i];
}

__global__ void k_redST(const float* __restrict__ part,
                        float* __restrict__ Smat, float* __restrict__ Tmat) {
  int k = blockIdx.x * blockDim.x + threadIdx.x;
  if (k < DD * DD) {
    float s = 0.f;
    for (int b = 0; b < GS_OUTER; ++b) s += part[(size_t)b * (DD * DD) + k];
    Smat[k] = s;
  } else {
    int kk = k - DD * DD;
    float s = 0.f;
    for (int b = 0; b < GT_OUTER; ++b) s += part[(size_t)(GS_OUTER + b) * (DD * DD) + kk];
    Tmat[kk] = s;
  }
}

// --- K6c: xs = xu_norm @ S (users), xt = xi_norm @ T (items) -> written to out -
__global__ void k_matvec(const float* __restrict__ x, const float* __restrict__ inv_norm,
                         const float* __restrict__ Smat, const float* __restrict__ Tmat,
                         float* __restrict__ out, int gU) {
  bool isI = (int)blockIdx.x >= gU;
  const float* M = isI ? Tmat : Smat;
  int row0  = isI ? NU : 0;
  int nrows = isI ? NI : NU;
  int bloc  = isI ? (int)blockIdx.x - gU : (int)blockIdx.x;
  int nb    = isI ? (int)gridDim.x - gU : gU;
  int lane = threadIdx.x & 63;
  float m_reg[DD];
#pragma unroll
  for (int a = 0; a < DD; ++a) m_reg[a] = M[a * DD + lane];
  int wid = bloc * (blockDim.x >> 6) + (threadIdx.x >> 6);
  int nw  = nb * (blockDim.x >> 6);
  for (int rr = wid; rr < nrows; rr += nw) {
    int r = row0 + rr;
    float v = x[(size_t)r * DD + lane] * inv_norm[r];
    float a0 = 0.f, a1 = 0.f, a2 = 0.f, a3 = 0.f;
#pragma unroll
    for (int a = 0; a < DD; a += 4) {
      a0 += __shfl(v, a)     * m_reg[a];
      a1 += __shfl(v, a + 1) * m_reg[a + 1];
      a2 += __shfl(v, a + 2) * m_reg[a + 2];
      a3 += __shfl(v, a + 3) * m_reg[a + 3];
    }
    out[(size_t)r * DD + lane] = (a0 + a1) + (a2 + a3);
  }
}

// --- K7: per-user pass, 16-lane-group float4 layout ----------------------------
__global__ void k_user3(const float* __restrict__ x, const float* __restrict__ inv_norm,
                        const int* __restrict__ uoff, const int2* __restrict__ uev,
                        const float* __restrict__ sum_xi, const float* __restrict__ sum_vi,
                        float2* __restrict__ te, float* __restrict__ out,
                        float* __restrict__ Gx, float* __restrict__ Gv, float* __restrict__ Gb) {
  __shared__ float gx_s[DD], gv_s[DD], gb_s;
  if (threadIdx.x < DD) { gx_s[threadIdx.x] = 0.f; gv_s[threadIdx.x] = 0.f; }
  if (threadIdx.x == 0) gb_s = 0.f;
  __syncthreads();
  int lane = threadIdx.x & 63;
  int g = lane >> 4, c = lane & 15;
  float gmask = (g == 0) ? 1.f : 0.f;
  int wid = blockIdx.x * (blockDim.x >> 6) + (threadIdx.x >> 6);
  int nw  = gridDim.x * (blockDim.x >> 6);
  const float4 sx4  = *(const float4*)(sum_xi + 4 * c);
  const float4 svl4 = *(const float4*)(sum_vi + 4 * c);
  float gxa0=0,gxa1=0,gxa2=0,gxa3=0, gva0=0,gva1=0,gva2=0,gva3=0, gb=0.f;
  float* tex = (float*)te;
  for (int uu = wid; uu < NU; uu += nw) {
    size_t ru = (size_t)uu * DD;
    int beg = uoff[uu], end2 = uoff[uu + 1];
    int deg = end2 - beg;
    float a1 = 1.0f / fmaxf((float)deg, 1.0f);
    float a2 = 1.0f / fmaxf((float)(NI - deg), 1.0f);
    float invu = inv_norm[uu];
    const float4 v4 = *(const float4*)(x + ru + 4 * c);
    float4 xu4 = make_float4(v4.x*invu, v4.y*invu, v4.z*invu, v4.w*invu);
    float Av0=0,Av1=0,Av2=0,Av3=0, sv0=0,sv1=0,sv2=0,sv3=0;
    float sA = 0.f, dm = 0.f;
    bool multi = deg > 64;
    int pi_l = 0;
    for (int base = beg; base < end2; base += 64) {
      int nb = end2 - base; if (nb > 64) nb = 64;
      int ii_l = 0; float inv_l = 0.f;
      if (lane < nb) {
        int2 m = uev[base + lane];
        ii_l = m.x; pi_l = m.y;
        inv_l = inv_norm[NU + m.x];
      }
      float dmc = 0.f;
      for (int k0 = 0; k0 < nb; k0 += 4) {
        int   ii  = __shfl(ii_l, k0 + g);
        float inj = __shfl(inv_l, k0 + g);
        float f   = (k0 + g < nb) ? 1.f : 0.f;
        const float4 r4 = *(const float4*)(x + (size_t)(NU + ii) * DD + 4 * c);
        float p = xu4.x*r4.x + xu4.y*r4.y + xu4.z*r4.z + xu4.w*r4.w;
        float d = rsum16(p) * inj;
        Av0 += d * r4.x; Av1 += d * r4.y; Av2 += d * r4.z; Av3 += d * r4.w;
        sv0 += f * r4.x; sv1 += f * r4.y; sv2 += f * r4.z; sv3 += f * r4.w;
        sA += d;
        float cand = __shfl(d, ((lane - k0) & 3) << 4);
        bool mine = (lane >= k0) && (lane < k0 + 4);
        dmc = mine ? cand : dmc;
      }
      if (multi && lane < nb) tex[2 * (size_t)pi_l] = dmc;
      dm = dmc;
    }
    sA  = xgrp2(sA);
    Av0 = xgrp2(Av0); Av1 = xgrp2(Av1); Av2 = xgrp2(Av2); Av3 = xgrp2(Av3);
    sv0 = xgrp2(sv0); sv1 = xgrp2(sv1); sv2 = xgrp2(sv2); sv3 = xgrp2(sv3);
    float bp = sA * a1;
    float pbn = xu4.x*sx4.x + xu4.y*sx4.y + xu4.z*sx4.z + xu4.w*sx4.w;
    float bn = (rsum16(pbn) - sA) * a2;
    float s1 = (ALPHA_C - bn) * a1;
    float s2 = (bp + ALPHA_C) * a2;
    if (!multi) {
      if (lane < deg) te[pi_l] = make_float2(dm * a1 + s1, dm * a2 - s2);
    } else {
      for (int k = beg + lane; k < end2; k += 64) {
        int2 m2 = uev[k];
        float dv = tex[2 * (size_t)m2.y];
        te[m2.y] = make_float2(dv * a1 + s1, dv * a2 - s2);
      }
    }
    const float4 xs4 = *(const float4*)(out + ru + 4 * c);
    float c12 = s1 + s2, a12 = a1 - a2;
    float rden = 1.0f / (2.0f * fmaxf(bp - bn + ALPHA_C, EPS_CLAMP));
    float o0 = (Av0 * a12 + sv0 * c12 + xs4.x * a2 - svl4.x * s2) * rden;
    float o1 = (Av1 * a12 + sv1 * c12 + xs4.y * a2 - svl4.y * s2) * rden;
    float o2 = (Av2 * a12 + sv2 * c12 + xs4.z * a2 - svl4.z * s2) * rden;
    float o3 = (Av3 * a12 + sv3 * c12 + xs4.w * a2 - svl4.w * s2) * rden;
    if (g == 0) *(float4*)(out + ru + 4 * c) = make_float4(o0, o1, o2, o3);
    float t2 = a2 * gmask, t3 = s2 * gmask;
    gxa0 += t2 * xu4.x; gxa1 += t2 * xu4.y; gxa2 += t2 * xu4.z; gxa3 += t2 * xu4.w;
    gva0 += t3 * v4.x;  gva1 += t3 * v4.y;  gva2 += t3 * v4.z;  gva3 += t3 * v4.w;
    if (lane == 0) gb += s2;
  }
  if (g == 0) {
    atomicAdd(&gx_s[4*c+0], gxa0); atomicAdd(&gx_s[4*c+1], gxa1);
    atomicAdd(&gx_s[4*c+2], gxa2); atomicAdd(&gx_s[4*c+3], gxa3);
    atomicAdd(&gv_s[4*c+0], gva0); atomicAdd(&gv_s[4*c+1], gva1);
    atomicAdd(&gv_s[4*c+2], gva2); atomicAdd(&gv_s[4*c+3], gva3);
  }
  if (lane == 0) atomicAdd(&gb_s, gb);
  __syncthreads();
  if (threadIdx.x < DD) {
    atomicAdd(&Gx[threadIdx.x], gx_s[threadIdx.x]);
    atomicAdd(&Gv[threadIdx.x], gv_s[threadIdx.x]);
  }
  if (threadIdx.x == 0) atomicAdd(Gb, gb_s);
}

// --- K8: per-item pass, 16-lane-group float4 layout -----------------------------
__global__ void k_item3(const float* __restrict__ x, const float* __restrict__ inv_norm,
                        const int* __restrict__ ioff, const int* __restrict__ iuu,
                        const float2* __restrict__ te,
                        const float* __restrict__ Gx, const float* __restrict__ Gv,
                        const float* __restrict__ Gb, float* __restrict__ out) {
  int lane = threadIdx.x & 63;
  int g = lane >> 4, c = lane & 15;
  int wid = blockIdx.x * (blockDim.x >> 6) + (threadIdx.x >> 6);
  int nw  = gridDim.x * (blockDim.x >> 6);
  const float4 Gx4 = *(const float4*)(Gx + 4 * c);
  const float4 Gv4 = *(const float4*)(Gv + 4 * c);
  float gb = *Gb;
  for (int j = wid; j < NI; j += nw) {
    int r = NU + j;
    size_t rr = (size_t)r * DD;
    float invi = inv_norm[r];
    const float4 vi4 = *(const float4*)(x + rr + 4 * c);
    float4 xi4 = make_float4(vi4.x*invi, vi4.y*invi, vi4.z*invi, vi4.w*invi);
    int beg = ioff[j], end2 = ioff[j + 1];
    float W0=0,W1=0,W2=0,W3=0, q1=0.f, q2=0.f;
    for (int base = beg; base < end2; base += 64) {
      int nb = end2 - base; if (nb > 64) nb = 64;
      int uu_l = 0; float glx = 0.f;
      if (lane < nb) {
        uu_l = iuu[base + lane];
        float2 t = te[base + lane];
        q1 += t.x; q2 += t.y;
        glx = t.x - t.y;
      }
      for (int k0 = 0; k0 < nb; k0 += 4) {
        int   ua = __shfl(uu_l, k0 + g);
        float ge = __shfl(glx,  k0 + g);
        const float4 r4 = *(const float4*)(x + (size_t)ua * DD + 4 * c);
        W0 += ge * r4.x; W1 += ge * r4.y; W2 += ge * r4.z; W3 += ge * r4.w;
      }
    }
    q1 = wsum(q1); q2 = wsum(q2);
    W0 = xgrp2(W0); W1 = xgrp2(W1); W2 = xgrp2(W2); W3 = xgrp2(W3);
    float pd = xi4.x*Gx4.x + xi4.y*Gx4.y + xi4.z*Gx4.z + xi4.w*Gx4.w;
    float di1 = q1;
    float di2 = -rsum16(pd) + q2 + gb;
    const float4 xt4 = *(const float4*)(out + rr + 4 * c);
    float rden = 1.0f / (fmaxf(di1, EPS_CLAMP) + fmaxf(di2, EPS_CLAMP));
    float o0 = (W0 + xt4.x - Gv4.x) * rden;
    float o1 = (W1 + xt4.y - Gv4.y) * rden;
    float o2 = (W2 + xt4.z - Gv4.z) * rden;
    float o3 = (W3 + xt4.w - Gv4.w) * rden;
    if (g == 0) *(float4*)(out + rr + 4 * c) = make_float4(o0, o1, o2, o3);
  }
}

extern "C" void kernel_launch(void* const* d_in, const int* in_sizes, int n_in,
                              void* d_out, int out_size, void* d_ws, size_t ws_size,
                              hipStream_t stream) {
  const float* x  = (const float*)d_in[0];
  const int*   u  = (const int*)d_in[1];
  const int*   it = (const int*)d_in[2];
  float* out = (float*)d_out;
  const int E = in_sizes[1];

  char* wsb = (char*)d_ws;
  size_t off = 0;
  auto alloc = [&](size_t elems) { void* p = wsb + off; off += elems * 4; return p; };

  // zero-init region (contiguous, first)
  int*   du     = (int*)alloc(100016);
  int*   di     = (int*)alloc(50016);
  float* sum_xi = (float*)alloc(64);
  float* sum_vi = (float*)alloc(64);
  float* Gx     = (float*)alloc(64);
  float* Gv     = (float*)alloc(64);
  float* Gb     = (float*)alloc(16);
  size_t zero_bytes = off;

  float* Smat   = (float*)alloc(4096);
  float* Tmat   = (float*)alloc(4096);
  float* part   = (float*)alloc((size_t)(GS_OUTER + GT_OUTER) * 4096);
  float*  inv_norm = (float*)alloc(150016);
  int*    uoff     = (int*)alloc(100016);
  int*    ucur     = (int*)alloc(100016);
  int*    ioff     = (int*)alloc(50016);
  int*    icur     = (int*)alloc(50016);
  int2*   uev      = (int2*)alloc(2000000);
  int*    iuu      = (int*)alloc(1000000);
  float2* te       = (float2*)alloc(2000000);

  hipMemsetAsync(d_ws, 0, zero_bytes, stream);

  k_norm_sums<<<1024, 256, 0, stream>>>(x, inv_norm, sum_xi, sum_vi);
  k_count<<<2048, 256, 0, stream>>>(u, it, du, di, E);
  k_scan2<<<2, 1024, 0, stream>>>(du, NU, uoff, ucur, di, NI, ioff, icur);
  k_scatter2<<<2048, 256, 0, stream>>>(u, it, E, ucur, icur, uev, iuu);
  k_outer3<<<GS_OUTER + GT_OUTER, 256, 0, stream>>>(x, inv_norm, du, part);
  k_redST<<<32, 256, 0, stream>>>(part, Smat, Tmat);
  k_matvec<<<1536, 256, 0, stream>>>(x, inv_norm, Smat, Tmat, out, 1024);
  k_user3<<<2048, 256, 0, stream>>>(x, inv_norm, uoff, uev, sum_xi, sum_vi,
                                    te, out, Gx, Gv, Gb);
  k_item3<<<2048, 256, 0, stream>>>(x, inv_norm, ioff, iuu, te,
                                    Gx, Gv, Gb, out);
}

// Round 8
// 769.604 us; speedup vs baseline: 2.9473x; 1.1822x over previous
//
#include <hip/hip_runtime.h>

#define NU 100000
#define NI 50000
#define DD 64
#define ALPHA_C 1.0f
#define EPS_CLAMP 1e-6f

__device__ __forceinline__ float rsum16(float v) {
  v += __shfl_xor(v, 1, 64);
  v += __shfl_xor(v, 2, 64);
  v += __shfl_xor(v, 4, 64);
  v += __shfl_xor(v, 8, 64);
  return v;
}
__device__ __forceinline__ float xgrp2(float v) {
  v += __shfl_xor(v, 16, 64);
  v += __shfl_xor(v, 32, 64);
  return v;
}
__device__ __forceinline__ float wsum(float v) { return xgrp2(rsum16(v)); }

// --- K1: norms + item column sums, float4 layout (4 rows per wave-iter) ------
__global__ void k_norm_sums(const float* __restrict__ x, float* __restrict__ inv_norm,
                            float* __restrict__ sum_xi, float* __restrict__ sum_vi) {
  __shared__ float sx_s[DD], sv_s[DD];
  if (threadIdx.x < DD) { sx_s[threadIdx.x] = 0.f; sv_s[threadIdx.x] = 0.f; }
  __syncthreads();
  int lane = threadIdx.x & 63;
  int g = lane >> 4, c = lane & 15;
  int wid = blockIdx.x * 4 + (threadIdx.x >> 6);
  int nw  = gridDim.x * 4;
  float sx0=0,sx1=0,sx2=0,sx3=0, sv0=0,sv1=0,sv2=0,sv3=0;
  for (int rb = wid * 4; rb < NU + NI; rb += nw * 4) {
    int r = rb + g;
    const float4 v4 = *(const float4*)(x + (size_t)r * DD + 4 * c);
    float p = v4.x*v4.x + v4.y*v4.y + v4.z*v4.z + v4.w*v4.w;
    p = rsum16(p);
    float inv = 1.0f / fmaxf(sqrtf(p), 1e-12f);
    if (c == 0) inv_norm[r] = inv;
    float fi = (r >= NU) ? 1.f : 0.f;
    float fx = fi * inv;
    sv0 += fi*v4.x; sv1 += fi*v4.y; sv2 += fi*v4.z; sv3 += fi*v4.w;
    sx0 += fx*v4.x; sx1 += fx*v4.y; sx2 += fx*v4.z; sx3 += fx*v4.w;
  }
  atomicAdd(&sx_s[4*c+0], sx0); atomicAdd(&sx_s[4*c+1], sx1);
  atomicAdd(&sx_s[4*c+2], sx2); atomicAdd(&sx_s[4*c+3], sx3);
  atomicAdd(&sv_s[4*c+0], sv0); atomicAdd(&sv_s[4*c+1], sv1);
  atomicAdd(&sv_s[4*c+2], sv2); atomicAdd(&sv_s[4*c+3], sv3);
  __syncthreads();
  if (threadIdx.x < DD) {
    atomicAdd(&sum_xi[threadIdx.x], sx_s[threadIdx.x]);
    atomicAdd(&sum_vi[threadIdx.x], sv_s[threadIdx.x]);
  }
}

// --- K2: degree counts -------------------------------------------------------
__global__ void k_count(const int* __restrict__ u, const int* __restrict__ it,
                        int* __restrict__ du, int* __restrict__ di, int E) {
  int t = blockIdx.x * blockDim.x + threadIdx.x;
  int stride = gridDim.x * blockDim.x;
  for (int e = t; e < E; e += stride) {
    atomicAdd(&du[u[e]], 1);
    atomicAdd(&di[it[e]], 1);
  }
}

// --- K3: two single-block exclusive scans ------------------------------------
__global__ void k_scan2(const int* __restrict__ cnt0, int n0, int* __restrict__ off0, int* __restrict__ cur0,
                        const int* __restrict__ cnt1, int n1, int* __restrict__ off1, int* __restrict__ cur1) {
  const int* cnt = blockIdx.x ? cnt1 : cnt0;
  int n          = blockIdx.x ? n1   : n0;
  int* off       = blockIdx.x ? off1 : off0;
  int* cur       = blockIdx.x ? cur1 : cur0;
  __shared__ int wsum_s[16];
  __shared__ int carry_s;
  int t = threadIdx.x, lane = t & 63, wv = t >> 6;
  if (t == 0) carry_s = 0;
  __syncthreads();
  for (int base = 0; base < n; base += 1024 * 8) {
    int v[8];
    int s = 0;
    int i0 = base + t * 8;
#pragma unroll
    for (int k = 0; k < 8; ++k) {
      int idx = i0 + k;
      v[k] = (idx < n) ? cnt[idx] : 0;
      s += v[k];
    }
    int incl = s;
#pragma unroll
    for (int d = 1; d < 64; d <<= 1) {
      int t2 = __shfl_up(incl, d, 64);
      if (lane >= d) incl += t2;
    }
    if (lane == 63) wsum_s[wv] = incl;
    __syncthreads();
    int woff = 0, total = 0;
#pragma unroll
    for (int w = 0; w < 16; ++w) {
      int ws_v = wsum_s[w];
      woff += (w < wv) ? ws_v : 0;
      total += ws_v;
    }
    int excl = carry_s + woff + incl - s;
#pragma unroll
    for (int k = 0; k < 8; ++k) {
      int idx = i0 + k;
      if (idx < n) { off[idx] = excl; cur[idx] = excl; }
      excl += v[k];
    }
    __syncthreads();
    if (t == 0) carry_s += total;
    __syncthreads();
  }
  if (t == 0) off[n] = carry_s;
}

// --- K4: scatter edges with embedded metadata ---------------------------------
__global__ void k_scatter2(const int* __restrict__ u, const int* __restrict__ it, int E,
                           int* __restrict__ ucur, int* __restrict__ icur,
                           int2* __restrict__ uev, int* __restrict__ iuu) {
  int t = blockIdx.x * blockDim.x + threadIdx.x;
  int stride = gridDim.x * blockDim.x;
  for (int e = t; e < E; e += stride) {
    int uu = u[e], ii = it[e];
    int pu = atomicAdd(&ucur[uu], 1);
    int pi = atomicAdd(&icur[ii], 1);
    uev[pu] = make_int2(ii, pi);
    iuu[pi] = uu;
  }
}

// --- K6: outer products — LDS-staged, 4x4 register tile per thread -------------
// blocks [0,GS_OUT): S over item rows; [GS_OUT,GRID_OUT): T over user rows.
// Each thread owns output tile (a0..a0+3, b0..b0+3); block partial -> part[].
#define GRID_OUT 256
#define GS_OUT 85
#define OCH 32
__global__ void k_outer4(const float* __restrict__ x, const float* __restrict__ inv_norm,
                         const int* __restrict__ du, float* __restrict__ part) {
  __shared__ float rows_s[OCH * DD];
  __shared__ float w_s[OCH];
  bool isT = (int)blockIdx.x >= GS_OUT;
  int bloc = isT ? (int)blockIdx.x - GS_OUT : (int)blockIdx.x;
  int nb   = isT ? (GRID_OUT - GS_OUT) : GS_OUT;
  int nrows = isT ? NU : NI;
  int row0  = isT ? 0 : NU;
  int t = threadIdx.x;
  int a0 = (t >> 4) << 2;
  int b0 = (t & 15) << 2;
  float acc[4][4];
#pragma unroll
  for (int i = 0; i < 4; ++i)
#pragma unroll
    for (int j = 0; j < 4; ++j) acc[i][j] = 0.f;
  int nch = (nrows + OCH - 1) / OCH;
  int limit = row0 + nrows;
  for (int ch = bloc; ch < nch; ch += nb) {
    int rbase = row0 + ch * OCH;
    __syncthreads();
    {
      const float4* src = (const float4*)(x + (size_t)rbase * DD);
      float4* dst = (float4*)rows_s;
      int r1 = rbase + (t >> 4);
      dst[t] = (r1 < limit) ? src[t] : make_float4(0.f, 0.f, 0.f, 0.f);
      int r2 = rbase + ((t + 256) >> 4);
      dst[t + 256] = (r2 < limit) ? src[t + 256] : make_float4(0.f, 0.f, 0.f, 0.f);
      if (t < OCH) {
        int r = rbase + t;
        float w = 0.f;
        if (r < limit) {
          w = inv_norm[r];
          if (isT) w /= fmaxf((float)NI - (float)du[r], 1.0f);
        }
        w_s[t] = w;
      }
    }
    __syncthreads();
#pragma unroll 8
    for (int r = 0; r < OCH; ++r) {
      float w = w_s[r];
      const float4 av = *(const float4*)(rows_s + r * DD + a0);
      const float4 bv = *(const float4*)(rows_s + r * DD + b0);
      float wa0 = av.x * w, wa1 = av.y * w, wa2 = av.z * w, wa3 = av.w * w;
      acc[0][0] += wa0 * bv.x; acc[0][1] += wa0 * bv.y; acc[0][2] += wa0 * bv.z; acc[0][3] += wa0 * bv.w;
      acc[1][0] += wa1 * bv.x; acc[1][1] += wa1 * bv.y; acc[1][2] += wa1 * bv.z; acc[1][3] += wa1 * bv.w;
      acc[2][0] += wa2 * bv.x; acc[2][1] += wa2 * bv.y; acc[2][2] += wa2 * bv.z; acc[2][3] += wa2 * bv.w;
      acc[3][0] += wa3 * bv.x; acc[3][1] += wa3 * bv.y; acc[3][2] += wa3 * bv.z; acc[3][3] += wa3 * bv.w;
    }
  }
  float* dst = part + (size_t)blockIdx.x * (DD * DD);
#pragma unroll
  for (int i = 0; i < 4; ++i)
    *(float4*)(dst + (size_t)(a0 + i) * DD + b0) =
        make_float4(acc[i][0], acc[i][1], acc[i][2], acc[i][3]);
}

// --- K6b: reduce partials into Smat/Tmat ---------------------------------------
__global__ void k_redST(const float* __restrict__ part,
                        float* __restrict__ Smat, float* __restrict__ Tmat) {
  int k = blockIdx.x * blockDim.x + threadIdx.x;  // 8192 threads
  if (k < DD * DD) {
    float s = 0.f;
    for (int b = 0; b < GS_OUT; ++b) s += part[(size_t)b * (DD * DD) + k];
    Smat[k] = s;
  } else {
    int kk = k - DD * DD;
    float s = 0.f;
    for (int b = GS_OUT; b < GRID_OUT; ++b) s += part[(size_t)b * (DD * DD) + kk];
    Tmat[kk] = s;
  }
}

// --- K6c: xs = xu_norm @ S (users), xt = xi_norm @ T (items) -> written to out -
__global__ void k_matvec(const float* __restrict__ x, const float* __restrict__ inv_norm,
                         const float* __restrict__ Smat, const float* __restrict__ Tmat,
                         float* __restrict__ out, int gU) {
  bool isI = (int)blockIdx.x >= gU;
  const float* M = isI ? Tmat : Smat;
  int row0  = isI ? NU : 0;
  int nrows = isI ? NI : NU;
  int bloc  = isI ? (int)blockIdx.x - gU : (int)blockIdx.x;
  int nb    = isI ? (int)gridDim.x - gU : gU;
  int lane = threadIdx.x & 63;
  float m_reg[DD];
#pragma unroll
  for (int a = 0; a < DD; ++a) m_reg[a] = M[a * DD + lane];
  int wid = bloc * (blockDim.x >> 6) + (threadIdx.x >> 6);
  int nw  = nb * (blockDim.x >> 6);
  for (int rr = wid; rr < nrows; rr += nw) {
    int r = row0 + rr;
    float v = x[(size_t)r * DD + lane] * inv_norm[r];
    float a0 = 0.f, a1 = 0.f, a2 = 0.f, a3 = 0.f;
#pragma unroll
    for (int a = 0; a < DD; a += 4) {
      a0 += __shfl(v, a)     * m_reg[a];
      a1 += __shfl(v, a + 1) * m_reg[a + 1];
      a2 += __shfl(v, a + 2) * m_reg[a + 2];
      a3 += __shfl(v, a + 3) * m_reg[a + 3];
    }
    out[(size_t)r * DD + lane] = (a0 + a1) + (a2 + a3);
  }
}

// --- K7: per-user pass, 16-lane-group float4 layout ----------------------------
__global__ void k_user3(const float* __restrict__ x, const float* __restrict__ inv_norm,
                        const int* __restrict__ uoff, const int2* __restrict__ uev,
                        const float* __restrict__ sum_xi, const float* __restrict__ sum_vi,
                        float2* __restrict__ te, float* __restrict__ out,
                        float* __restrict__ Gx, float* __restrict__ Gv, float* __restrict__ Gb) {
  __shared__ float gx_s[DD], gv_s[DD], gb_s;
  if (threadIdx.x < DD) { gx_s[threadIdx.x] = 0.f; gv_s[threadIdx.x] = 0.f; }
  if (threadIdx.x == 0) gb_s = 0.f;
  __syncthreads();
  int lane = threadIdx.x & 63;
  int g = lane >> 4, c = lane & 15;
  float gmask = (g == 0) ? 1.f : 0.f;
  int wid = blockIdx.x * (blockDim.x >> 6) + (threadIdx.x >> 6);
  int nw  = gridDim.x * (blockDim.x >> 6);
  const float4 sx4  = *(const float4*)(sum_xi + 4 * c);
  const float4 svl4 = *(const float4*)(sum_vi + 4 * c);
  float gxa0=0,gxa1=0,gxa2=0,gxa3=0, gva0=0,gva1=0,gva2=0,gva3=0, gb=0.f;
  float* tex = (float*)te;
  for (int uu = wid; uu < NU; uu += nw) {
    size_t ru = (size_t)uu * DD;
    int beg = uoff[uu], end2 = uoff[uu + 1];
    int deg = end2 - beg;
    float a1 = 1.0f / fmaxf((float)deg, 1.0f);
    float a2 = 1.0f / fmaxf((float)(NI - deg), 1.0f);
    float invu = inv_norm[uu];
    const float4 v4 = *(const float4*)(x + ru + 4 * c);
    float4 xu4 = make_float4(v4.x*invu, v4.y*invu, v4.z*invu, v4.w*invu);
    float Av0=0,Av1=0,Av2=0,Av3=0, sv0=0,sv1=0,sv2=0,sv3=0;
    float sA = 0.f, dm = 0.f;
    bool multi = deg > 64;
    int pi_l = 0;
    for (int base = beg; base < end2; base += 64) {
      int nb = end2 - base; if (nb > 64) nb = 64;
      int ii_l = 0; float inv_l = 0.f;
      if (lane < nb) {
        int2 m = uev[base + lane];
        ii_l = m.x; pi_l = m.y;
        inv_l = inv_norm[NU + m.x];
      }
      float dmc = 0.f;
      for (int k0 = 0; k0 < nb; k0 += 4) {
        int   ii  = __shfl(ii_l, k0 + g);
        float inj = __shfl(inv_l, k0 + g);
        float f   = (k0 + g < nb) ? 1.f : 0.f;
        const float4 r4 = *(const float4*)(x + (size_t)(NU + ii) * DD + 4 * c);
        float p = xu4.x*r4.x + xu4.y*r4.y + xu4.z*r4.z + xu4.w*r4.w;
        float d = rsum16(p) * inj;
        Av0 += d * r4.x; Av1 += d * r4.y; Av2 += d * r4.z; Av3 += d * r4.w;
        sv0 += f * r4.x; sv1 += f * r4.y; sv2 += f * r4.z; sv3 += f * r4.w;
        sA += d;
        float cand = __shfl(d, ((lane - k0) & 3) << 4);
        bool mine = (lane >= k0) && (lane < k0 + 4);
        dmc = mine ? cand : dmc;
      }
      if (multi && lane < nb) tex[2 * (size_t)pi_l] = dmc;
      dm = dmc;
    }
    sA  = xgrp2(sA);
    Av0 = xgrp2(Av0); Av1 = xgrp2(Av1); Av2 = xgrp2(Av2); Av3 = xgrp2(Av3);
    sv0 = xgrp2(sv0); sv1 = xgrp2(sv1); sv2 = xgrp2(sv2); sv3 = xgrp2(sv3);
    float bp = sA * a1;
    float pbn = xu4.x*sx4.x + xu4.y*sx4.y + xu4.z*sx4.z + xu4.w*sx4.w;
    float bn = (rsum16(pbn) - sA) * a2;
    float s1 = (ALPHA_C - bn) * a1;
    float s2 = (bp + ALPHA_C) * a2;
    if (!multi) {
      if (lane < deg) te[pi_l] = make_float2(dm * a1 + s1, dm * a2 - s2);
    } else {
      for (int k = beg + lane; k < end2; k += 64) {
        int2 m2 = uev[k];
        float dv = tex[2 * (size_t)m2.y];
        te[m2.y] = make_float2(dv * a1 + s1, dv * a2 - s2);
      }
    }
    const float4 xs4 = *(const float4*)(out + ru + 4 * c);
    float c12 = s1 + s2, a12 = a1 - a2;
    float rden = 1.0f / (2.0f * fmaxf(bp - bn + ALPHA_C, EPS_CLAMP));
    float o0 = (Av0 * a12 + sv0 * c12 + xs4.x * a2 - svl4.x * s2) * rden;
    float o1 = (Av1 * a12 + sv1 * c12 + xs4.y * a2 - svl4.y * s2) * rden;
    float o2 = (Av2 * a12 + sv2 * c12 + xs4.z * a2 - svl4.z * s2) * rden;
    float o3 = (Av3 * a12 + sv3 * c12 + xs4.w * a2 - svl4.w * s2) * rden;
    if (g == 0) *(float4*)(out + ru + 4 * c) = make_float4(o0, o1, o2, o3);
    float t2 = a2 * gmask, t3 = s2 * gmask;
    gxa0 += t2 * xu4.x; gxa1 += t2 * xu4.y; gxa2 += t2 * xu4.z; gxa3 += t2 * xu4.w;
    gva0 += t3 * v4.x;  gva1 += t3 * v4.y;  gva2 += t3 * v4.z;  gva3 += t3 * v4.w;
    if (lane == 0) gb += s2;
  }
  if (g == 0) {
    atomicAdd(&gx_s[4*c+0], gxa0); atomicAdd(&gx_s[4*c+1], gxa1);
    atomicAdd(&gx_s[4*c+2], gxa2); atomicAdd(&gx_s[4*c+3], gxa3);
    atomicAdd(&gv_s[4*c+0], gva0); atomicAdd(&gv_s[4*c+1], gva1);
    atomicAdd(&gv_s[4*c+2], gva2); atomicAdd(&gv_s[4*c+3], gva3);
  }
  if (lane == 0) atomicAdd(&gb_s, gb);
  __syncthreads();
  if (threadIdx.x < DD) {
    atomicAdd(&Gx[threadIdx.x], gx_s[threadIdx.x]);
    atomicAdd(&Gv[threadIdx.x], gv_s[threadIdx.x]);
  }
  if (threadIdx.x == 0) atomicAdd(Gb, gb_s);
}

// --- K8: per-item pass, 16-lane-group float4 layout -----------------------------
__global__ void k_item3(const float* __restrict__ x, const float* __restrict__ inv_norm,
                        const int* __restrict__ ioff, const int* __restrict__ iuu,
                        const float2* __restrict__ te,
                        const float* __restrict__ Gx, const float* __restrict__ Gv,
                        const float* __restrict__ Gb, float* __restrict__ out) {
  int lane = threadIdx.x & 63;
  int g = lane >> 4, c = lane & 15;
  int wid = blockIdx.x * (blockDim.x >> 6) + (threadIdx.x >> 6);
  int nw  = gridDim.x * (blockDim.x >> 6);
  const float4 Gx4 = *(const float4*)(Gx + 4 * c);
  const float4 Gv4 = *(const float4*)(Gv + 4 * c);
  float gb = *Gb;
  for (int j = wid; j < NI; j += nw) {
    int r = NU + j;
    size_t rr = (size_t)r * DD;
    float invi = inv_norm[r];
    const float4 vi4 = *(const float4*)(x + rr + 4 * c);
    float4 xi4 = make_float4(vi4.x*invi, vi4.y*invi, vi4.z*invi, vi4.w*invi);
    int beg = ioff[j], end2 = ioff[j + 1];
    float W0=0,W1=0,W2=0,W3=0, q1=0.f, q2=0.f;
    for (int base = beg; base < end2; base += 64) {
      int nb = end2 - base; if (nb > 64) nb = 64;
      int uu_l = 0; float glx = 0.f;
      if (lane < nb) {
        uu_l = iuu[base + lane];
        float2 t = te[base + lane];
        q1 += t.x; q2 += t.y;
        glx = t.x - t.y;
      }
      for (int k0 = 0; k0 < nb; k0 += 4) {
        int   ua = __shfl(uu_l, k0 + g);
        float ge = __shfl(glx,  k0 + g);
        const float4 r4 = *(const float4*)(x + (size_t)ua * DD + 4 * c);
        W0 += ge * r4.x; W1 += ge * r4.y; W2 += ge * r4.z; W3 += ge * r4.w;
      }
    }
    q1 = wsum(q1); q2 = wsum(q2);
    W0 = xgrp2(W0); W1 = xgrp2(W1); W2 = xgrp2(W2); W3 = xgrp2(W3);
    float pd = xi4.x*Gx4.x + xi4.y*Gx4.y + xi4.z*Gx4.z + xi4.w*Gx4.w;
    float di1 = q1;
    float di2 = -rsum16(pd) + q2 + gb;
    const float4 xt4 = *(const float4*)(out + rr + 4 * c);
    float rden = 1.0f / (fmaxf(di1, EPS_CLAMP) + fmaxf(di2, EPS_CLAMP));
    float o0 = (W0 + xt4.x - Gv4.x) * rden;
    float o1 = (W1 + xt4.y - Gv4.y) * rden;
    float o2 = (W2 + xt4.z - Gv4.z) * rden;
    float o3 = (W3 + xt4.w - Gv4.w) * rden;
    if (g == 0) *(float4*)(out + rr + 4 * c) = make_float4(o0, o1, o2, o3);
  }
}

extern "C" void kernel_launch(void* const* d_in, const int* in_sizes, int n_in,
                              void* d_out, int out_size, void* d_ws, size_t ws_size,
                              hipStream_t stream) {
  const float* x  = (const float*)d_in[0];
  const int*   u  = (const int*)d_in[1];
  const int*   it = (const int*)d_in[2];
  float* out = (float*)d_out;
  const int E = in_sizes[1];

  char* wsb = (char*)d_ws;
  size_t off = 0;
  auto alloc = [&](size_t elems) { void* p = wsb + off; off += elems * 4; return p; };

  // zero-init region (contiguous, first)
  int*   du     = (int*)alloc(100016);
  int*   di     = (int*)alloc(50016);
  float* sum_xi = (float*)alloc(64);
  float* sum_vi = (float*)alloc(64);
  float* Gx     = (float*)alloc(64);
  float* Gv     = (float*)alloc(64);
  float* Gb     = (float*)alloc(16);
  size_t zero_bytes = off;

  float* Smat   = (float*)alloc(4096);
  float* Tmat   = (float*)alloc(4096);
  float* part   = (float*)alloc((size_t)GRID_OUT * 4096);
  float*  inv_norm = (float*)alloc(150016);
  int*    uoff     = (int*)alloc(100016);
  int*    ucur     = (int*)alloc(100016);
  int*    ioff     = (int*)alloc(50016);
  int*    icur     = (int*)alloc(50016);
  int2*   uev      = (int2*)alloc(2000000);
  int*    iuu      = (int*)alloc(1000000);
  float2* te       = (float2*)alloc(2000000);

  hipMemsetAsync(d_ws, 0, zero_bytes, stream);

  k_norm_sums<<<1024, 256, 0, stream>>>(x, inv_norm, sum_xi, sum_vi);
  k_count<<<2048, 256, 0, stream>>>(u, it, du, di, E);
  k_scan2<<<2, 1024, 0, stream>>>(du, NU, uoff, ucur, di, NI, ioff, icur);
  k_scatter2<<<2048, 256, 0, stream>>>(u, it, E, ucur, icur, uev, iuu);
  k_outer4<<<GRID_OUT, 256, 0, stream>>>(x, inv_norm, du, part);
  k_redST<<<32, 256, 0, stream>>>(part, Smat, Tmat);
  k_matvec<<<1536, 256, 0, stream>>>(x, inv_norm, Smat, Tmat, out, 1024);
  k_user3<<<2048, 256, 0, stream>>>(x, inv_norm, uoff, uev, sum_xi, sum_vi,
                                    te, out, Gx, Gv, Gb);
  k_item3<<<2048, 256, 0, stream>>>(x, inv_norm, ioff, iuu, te,
                                    Gx, Gv, Gb, out);
}

// Round 9
// 630.545 us; speedup vs baseline: 3.5972x; 1.2205x over previous
//
#include <hip/hip_runtime.h>

#define NU 100000
#define NI 50000
#define DD 64
#define ALPHA_C 1.0f
#define EPS_CLAMP 1e-6f

__device__ __forceinline__ float rsum16(float v) {
  v += __shfl_xor(v, 1, 64);
  v += __shfl_xor(v, 2, 64);
  v += __shfl_xor(v, 4, 64);
  v += __shfl_xor(v, 8, 64);
  return v;
}
__device__ __forceinline__ float xgrp2(float v) {
  v += __shfl_xor(v, 16, 64);
  v += __shfl_xor(v, 32, 64);
  return v;
}
__device__ __forceinline__ float wsum(float v) { return xgrp2(rsum16(v)); }

// --- K1: norms + item column sums, float4 layout ------------------------------
__global__ void k_norm_sums(const float* __restrict__ x, float* __restrict__ inv_norm,
                            float* __restrict__ sum_xi, float* __restrict__ sum_vi) {
  __shared__ float sx_s[DD], sv_s[DD];
  if (threadIdx.x < DD) { sx_s[threadIdx.x] = 0.f; sv_s[threadIdx.x] = 0.f; }
  __syncthreads();
  int lane = threadIdx.x & 63;
  int g = lane >> 4, c = lane & 15;
  int wid = blockIdx.x * 4 + (threadIdx.x >> 6);
  int nw  = gridDim.x * 4;
  float sx0=0,sx1=0,sx2=0,sx3=0, sv0=0,sv1=0,sv2=0,sv3=0;
  for (int rb = wid * 4; rb < NU + NI; rb += nw * 4) {
    int r = rb + g;
    const float4 v4 = *(const float4*)(x + (size_t)r * DD + 4 * c);
    float p = v4.x*v4.x + v4.y*v4.y + v4.z*v4.z + v4.w*v4.w;
    p = rsum16(p);
    float inv = 1.0f / fmaxf(sqrtf(p), 1e-12f);
    if (c == 0) inv_norm[r] = inv;
    float fi = (r >= NU) ? 1.f : 0.f;
    float fx = fi * inv;
    sv0 += fi*v4.x; sv1 += fi*v4.y; sv2 += fi*v4.z; sv3 += fi*v4.w;
    sx0 += fx*v4.x; sx1 += fx*v4.y; sx2 += fx*v4.z; sx3 += fx*v4.w;
  }
  atomicAdd(&sx_s[4*c+0], sx0); atomicAdd(&sx_s[4*c+1], sx1);
  atomicAdd(&sx_s[4*c+2], sx2); atomicAdd(&sx_s[4*c+3], sx3);
  atomicAdd(&sv_s[4*c+0], sv0); atomicAdd(&sv_s[4*c+1], sv1);
  atomicAdd(&sv_s[4*c+2], sv2); atomicAdd(&sv_s[4*c+3], sv3);
  __syncthreads();
  if (threadIdx.x < DD) {
    atomicAdd(&sum_xi[threadIdx.x], sx_s[threadIdx.x]);
    atomicAdd(&sum_vi[threadIdx.x], sv_s[threadIdx.x]);
  }
}

// --- K2: degree counts + per-edge ranks (linear writes) ------------------------
__global__ void k_count2(const int* __restrict__ u, const int* __restrict__ it,
                         int* __restrict__ du, int* __restrict__ di,
                         int* __restrict__ ru_, int* __restrict__ ri_, int E) {
  int t = blockIdx.x * blockDim.x + threadIdx.x;
  int stride = gridDim.x * blockDim.x;
  for (int e = t; e < E; e += stride) {
    ru_[e] = atomicAdd(&du[u[e]], 1);
    ri_[e] = atomicAdd(&di[it[e]], 1);
  }
}

// --- K3: two single-block exclusive scans --------------------------------------
__global__ void k_scan2(const int* __restrict__ cnt0, int n0, int* __restrict__ off0,
                        const int* __restrict__ cnt1, int n1, int* __restrict__ off1) {
  const int* cnt = blockIdx.x ? cnt1 : cnt0;
  int n          = blockIdx.x ? n1   : n0;
  int* off       = blockIdx.x ? off1 : off0;
  __shared__ int wsum_s[16];
  __shared__ int carry_s;
  int t = threadIdx.x, lane = t & 63, wv = t >> 6;
  if (t == 0) carry_s = 0;
  __syncthreads();
  for (int base = 0; base < n; base += 1024 * 8) {
    int v[8];
    int s = 0;
    int i0 = base + t * 8;
#pragma unroll
    for (int k = 0; k < 8; ++k) {
      int idx = i0 + k;
      v[k] = (idx < n) ? cnt[idx] : 0;
      s += v[k];
    }
    int incl = s;
#pragma unroll
    for (int d = 1; d < 64; d <<= 1) {
      int t2 = __shfl_up(incl, d, 64);
      if (lane >= d) incl += t2;
    }
    if (lane == 63) wsum_s[wv] = incl;
    __syncthreads();
    int woff = 0, total = 0;
#pragma unroll
    for (int w = 0; w < 16; ++w) {
      int ws_v = wsum_s[w];
      woff += (w < wv) ? ws_v : 0;
      total += ws_v;
    }
    int excl = carry_s + woff + incl - s;
#pragma unroll
    for (int k = 0; k < 8; ++k) {
      int idx = i0 + k;
      if (idx < n) off[idx] = excl;
      excl += v[k];
    }
    __syncthreads();
    if (t == 0) carry_s += total;
    __syncthreads();
  }
  if (t == 0) off[n] = carry_s;
}

// --- K4: atomic-free scatter, nontemporal stores --------------------------------
__global__ void k_scatter3(const int* __restrict__ u, const int* __restrict__ it,
                           const int* __restrict__ ru_, const int* __restrict__ ri_,
                           const int* __restrict__ uoff, const int* __restrict__ ioff, int E,
                           int* __restrict__ uev, unsigned long long* __restrict__ iue) {
  int t = blockIdx.x * blockDim.x + threadIdx.x;
  int stride = gridDim.x * blockDim.x;
  for (int e = t; e < E; e += stride) {
    int uu = u[e], ii = it[e];
    int pu = uoff[uu] + ru_[e];
    int pi = ioff[ii] + ri_[e];
    __builtin_nontemporal_store(ii, &uev[pu]);
    unsigned long long packed = (unsigned long long)(unsigned)uu |
                                ((unsigned long long)(unsigned)pu << 32);
    __builtin_nontemporal_store(packed, &iue[pi]);
  }
}

// --- K6: outer products — LDS-staged, 4x4 register tile per thread ---------------
#define GRID_OUT 256
#define GS_OUT 85
#define OCH 32
__global__ void k_outer4(const float* __restrict__ x, const float* __restrict__ inv_norm,
                         const int* __restrict__ du, float* __restrict__ part) {
  __shared__ float rows_s[OCH * DD];
  __shared__ float w_s[OCH];
  bool isT = (int)blockIdx.x >= GS_OUT;
  int bloc = isT ? (int)blockIdx.x - GS_OUT : (int)blockIdx.x;
  int nb   = isT ? (GRID_OUT - GS_OUT) : GS_OUT;
  int nrows = isT ? NU : NI;
  int row0  = isT ? 0 : NU;
  int t = threadIdx.x;
  int a0 = (t >> 4) << 2;
  int b0 = (t & 15) << 2;
  float acc[4][4];
#pragma unroll
  for (int i = 0; i < 4; ++i)
#pragma unroll
    for (int j = 0; j < 4; ++j) acc[i][j] = 0.f;
  int nch = (nrows + OCH - 1) / OCH;
  int limit = row0 + nrows;
  for (int ch = bloc; ch < nch; ch += nb) {
    int rbase = row0 + ch * OCH;
    __syncthreads();
    {
      const float4* src = (const float4*)(x + (size_t)rbase * DD);
      float4* dst = (float4*)rows_s;
      int r1 = rbase + (t >> 4);
      dst[t] = (r1 < limit) ? src[t] : make_float4(0.f, 0.f, 0.f, 0.f);
      int r2 = rbase + ((t + 256) >> 4);
      dst[t + 256] = (r2 < limit) ? src[t + 256] : make_float4(0.f, 0.f, 0.f, 0.f);
      if (t < OCH) {
        int r = rbase + t;
        float w = 0.f;
        if (r < limit) {
          w = inv_norm[r];
          if (isT) w /= fmaxf((float)NI - (float)du[r], 1.0f);
        }
        w_s[t] = w;
      }
    }
    __syncthreads();
#pragma unroll 8
    for (int r = 0; r < OCH; ++r) {
      float w = w_s[r];
      const float4 av = *(const float4*)(rows_s + r * DD + a0);
      const float4 bv = *(const float4*)(rows_s + r * DD + b0);
      float wa0 = av.x * w, wa1 = av.y * w, wa2 = av.z * w, wa3 = av.w * w;
      acc[0][0] += wa0 * bv.x; acc[0][1] += wa0 * bv.y; acc[0][2] += wa0 * bv.z; acc[0][3] += wa0 * bv.w;
      acc[1][0] += wa1 * bv.x; acc[1][1] += wa1 * bv.y; acc[1][2] += wa1 * bv.z; acc[1][3] += wa1 * bv.w;
      acc[2][0] += wa2 * bv.x; acc[2][1] += wa2 * bv.y; acc[2][2] += wa2 * bv.z; acc[2][3] += wa2 * bv.w;
      acc[3][0] += wa3 * bv.x; acc[3][1] += wa3 * bv.y; acc[3][2] += wa3 * bv.z; acc[3][3] += wa3 * bv.w;
    }
  }
  float* dst = part + (size_t)blockIdx.x * (DD * DD);
#pragma unroll
  for (int i = 0; i < 4; ++i)
    *(float4*)(dst + (size_t)(a0 + i) * DD + b0) =
        make_float4(acc[i][0], acc[i][1], acc[i][2], acc[i][3]);
}

// --- K6b: reduce partials into Smat/Tmat ------------------------------------------
__global__ void k_redST(const float* __restrict__ part,
                        float* __restrict__ Smat, float* __restrict__ Tmat) {
  int k = blockIdx.x * blockDim.x + threadIdx.x;
  if (k < DD * DD) {
    float s = 0.f;
    for (int b = 0; b < GS_OUT; ++b) s += part[(size_t)b * (DD * DD) + k];
    Smat[k] = s;
  } else {
    int kk = k - DD * DD;
    float s = 0.f;
    for (int b = GS_OUT; b < GRID_OUT; ++b) s += part[(size_t)b * (DD * DD) + kk];
    Tmat[kk] = s;
  }
}

// --- K6c: xs/xt matvec -> out ------------------------------------------------------
__global__ void k_matvec(const float* __restrict__ x, const float* __restrict__ inv_norm,
                         const float* __restrict__ Smat, const float* __restrict__ Tmat,
                         float* __restrict__ out, int gU) {
  bool isI = (int)blockIdx.x >= gU;
  const float* M = isI ? Tmat : Smat;
  int row0  = isI ? NU : 0;
  int nrows = isI ? NI : NU;
  int bloc  = isI ? (int)blockIdx.x - gU : (int)blockIdx.x;
  int nb    = isI ? (int)gridDim.x - gU : gU;
  int lane = threadIdx.x & 63;
  float m_reg[DD];
#pragma unroll
  for (int a = 0; a < DD; ++a) m_reg[a] = M[a * DD + lane];
  int wid = bloc * (blockDim.x >> 6) + (threadIdx.x >> 6);
  int nw  = nb * (blockDim.x >> 6);
  for (int rr = wid; rr < nrows; rr += nw) {
    int r = row0 + rr;
    float v = x[(size_t)r * DD + lane] * inv_norm[r];
    float a0 = 0.f, a1 = 0.f, a2 = 0.f, a3 = 0.f;
#pragma unroll
    for (int a = 0; a < DD; a += 4) {
      a0 += __shfl(v, a)     * m_reg[a];
      a1 += __shfl(v, a + 1) * m_reg[a + 1];
      a2 += __shfl(v, a + 2) * m_reg[a + 2];
      a3 += __shfl(v, a + 3) * m_reg[a + 3];
    }
    out[(size_t)r * DD + lane] = (a0 + a1) + (a2 + a3);
  }
}

// --- K7: per-user pass — linear d_raw writes, per-user usc --------------------------
__global__ void k_user4(const float* __restrict__ x, const float* __restrict__ inv_norm,
                        const int* __restrict__ uoff, const int* __restrict__ uev,
                        const float* __restrict__ sum_xi, const float* __restrict__ sum_vi,
                        float* __restrict__ d_raw, float4* __restrict__ usc,
                        float* __restrict__ out,
                        float* __restrict__ Gx, float* __restrict__ Gv, float* __restrict__ Gb) {
  __shared__ float gx_s[DD], gv_s[DD], gb_s;
  if (threadIdx.x < DD) { gx_s[threadIdx.x] = 0.f; gv_s[threadIdx.x] = 0.f; }
  if (threadIdx.x == 0) gb_s = 0.f;
  __syncthreads();
  int lane = threadIdx.x & 63;
  int g = lane >> 4, c = lane & 15;
  float gmask = (g == 0) ? 1.f : 0.f;
  int wid = blockIdx.x * (blockDim.x >> 6) + (threadIdx.x >> 6);
  int nw  = gridDim.x * (blockDim.x >> 6);
  const float4 sx4  = *(const float4*)(sum_xi + 4 * c);
  const float4 svl4 = *(const float4*)(sum_vi + 4 * c);
  float gxa0=0,gxa1=0,gxa2=0,gxa3=0, gva0=0,gva1=0,gva2=0,gva3=0, gb=0.f;
  for (int uu = wid; uu < NU; uu += nw) {
    size_t ru = (size_t)uu * DD;
    int beg = uoff[uu], end2 = uoff[uu + 1];
    int deg = end2 - beg;
    float a1 = 1.0f / fmaxf((float)deg, 1.0f);
    float a2 = 1.0f / fmaxf((float)(NI - deg), 1.0f);
    float invu = inv_norm[uu];
    const float4 v4 = *(const float4*)(x + ru + 4 * c);
    float4 xu4 = make_float4(v4.x*invu, v4.y*invu, v4.z*invu, v4.w*invu);
    float Av0=0,Av1=0,Av2=0,Av3=0, sv0=0,sv1=0,sv2=0,sv3=0;
    float sA = 0.f;
    for (int base = beg; base < end2; base += 64) {
      int nb = end2 - base; if (nb > 64) nb = 64;
      int ii_l = 0; float inv_l = 0.f;
      if (lane < nb) {
        ii_l = uev[base + lane];
        inv_l = inv_norm[NU + ii_l];
      }
      for (int k0 = 0; k0 < nb; k0 += 4) {
        int   ii  = __shfl(ii_l, k0 + g);
        float inj = __shfl(inv_l, k0 + g);
        float f   = (k0 + g < nb) ? 1.f : 0.f;
        const float4 r4 = *(const float4*)(x + (size_t)(NU + ii) * DD + 4 * c);
        float p = xu4.x*r4.x + xu4.y*r4.y + xu4.z*r4.z + xu4.w*r4.w;
        float d = rsum16(p) * inj;
        Av0 += d * r4.x; Av1 += d * r4.y; Av2 += d * r4.z; Av3 += d * r4.w;
        sv0 += f * r4.x; sv1 += f * r4.y; sv2 += f * r4.z; sv3 += f * r4.w;
        sA += d;
        if (c == 0 && k0 + g < nb) d_raw[base + k0 + g] = d;  // linear per-user run
      }
    }
    sA  = xgrp2(sA);
    Av0 = xgrp2(Av0); Av1 = xgrp2(Av1); Av2 = xgrp2(Av2); Av3 = xgrp2(Av3);
    sv0 = xgrp2(sv0); sv1 = xgrp2(sv1); sv2 = xgrp2(sv2); sv3 = xgrp2(sv3);
    float bp = sA * a1;
    float pbn = xu4.x*sx4.x + xu4.y*sx4.y + xu4.z*sx4.z + xu4.w*sx4.w;
    float bn = (rsum16(pbn) - sA) * a2;
    float s1 = (ALPHA_C - bn) * a1;
    float s2 = (bp + ALPHA_C) * a2;
    if (lane == 0) usc[uu] = make_float4(a1, a2, s1, s2);
    const float4 xs4 = *(const float4*)(out + ru + 4 * c);
    float c12 = s1 + s2, a12 = a1 - a2;
    float rden = 1.0f / (2.0f * fmaxf(bp - bn + ALPHA_C, EPS_CLAMP));
    float o0 = (Av0 * a12 + sv0 * c12 + xs4.x * a2 - svl4.x * s2) * rden;
    float o1 = (Av1 * a12 + sv1 * c12 + xs4.y * a2 - svl4.y * s2) * rden;
    float o2 = (Av2 * a12 + sv2 * c12 + xs4.z * a2 - svl4.z * s2) * rden;
    float o3 = (Av3 * a12 + sv3 * c12 + xs4.w * a2 - svl4.w * s2) * rden;
    if (g == 0) *(float4*)(out + ru + 4 * c) = make_float4(o0, o1, o2, o3);
    float t2 = a2 * gmask, t3 = s2 * gmask;
    gxa0 += t2 * xu4.x; gxa1 += t2 * xu4.y; gxa2 += t2 * xu4.z; gxa3 += t2 * xu4.w;
    gva0 += t3 * v4.x;  gva1 += t3 * v4.y;  gva2 += t3 * v4.z;  gva3 += t3 * v4.w;
    if (lane == 0) gb += s2;
  }
  if (g == 0) {
    atomicAdd(&gx_s[4*c+0], gxa0); atomicAdd(&gx_s[4*c+1], gxa1);
    atomicAdd(&gx_s[4*c+2], gxa2); atomicAdd(&gx_s[4*c+3], gxa3);
    atomicAdd(&gv_s[4*c+0], gva0); atomicAdd(&gv_s[4*c+1], gva1);
    atomicAdd(&gv_s[4*c+2], gva2); atomicAdd(&gv_s[4*c+3], gva3);
  }
  if (lane == 0) atomicAdd(&gb_s, gb);
  __syncthreads();
  if (threadIdx.x < DD) {
    atomicAdd(&Gx[threadIdx.x], gx_s[threadIdx.x]);
    atomicAdd(&Gv[threadIdx.x], gv_s[threadIdx.x]);
  }
  if (threadIdx.x == 0) atomicAdd(Gb, gb_s);
}

// --- K8: per-item pass — reconstruct t1,t2 from d_raw + usc --------------------------
__global__ void k_item4(const float* __restrict__ x, const float* __restrict__ inv_norm,
                        const int* __restrict__ ioff, const uint2* __restrict__ iue,
                        const float* __restrict__ d_raw, const float4* __restrict__ usc,
                        const float* __restrict__ Gx, const float* __restrict__ Gv,
                        const float* __restrict__ Gb, float* __restrict__ out) {
  int lane = threadIdx.x & 63;
  int g = lane >> 4, c = lane & 15;
  int wid = blockIdx.x * (blockDim.x >> 6) + (threadIdx.x >> 6);
  int nw  = gridDim.x * (blockDim.x >> 6);
  const float4 Gx4 = *(const float4*)(Gx + 4 * c);
  const float4 Gv4 = *(const float4*)(Gv + 4 * c);
  float gb = *Gb;
  for (int j = wid; j < NI; j += nw) {
    int r = NU + j;
    size_t rr = (size_t)r * DD;
    float invi = inv_norm[r];
    const float4 vi4 = *(const float4*)(x + rr + 4 * c);
    float4 xi4 = make_float4(vi4.x*invi, vi4.y*invi, vi4.z*invi, vi4.w*invi);
    int beg = ioff[j], end2 = ioff[j + 1];
    float W0=0,W1=0,W2=0,W3=0, q1=0.f, q2=0.f;
    for (int base = beg; base < end2; base += 64) {
      int nb = end2 - base; if (nb > 64) nb = 64;
      int uu_l = 0; float glx = 0.f;
      if (lane < nb) {
        uint2 m = iue[base + lane];
        uu_l = (int)m.x;
        float d = d_raw[m.y];
        float4 cc = usc[uu_l];
        float t1 = d * cc.x + cc.z;
        float t2 = d * cc.y - cc.w;
        q1 += t1; q2 += t2;
        glx = t1 - t2;
      }
      for (int k0 = 0; k0 < nb; k0 += 4) {
        int   ua = __shfl(uu_l, k0 + g);
        float ge = __shfl(glx,  k0 + g);
        const float4 r4 = *(const float4*)(x + (size_t)ua * DD + 4 * c);
        W0 += ge * r4.x; W1 += ge * r4.y; W2 += ge * r4.z; W3 += ge * r4.w;
      }
    }
    q1 = wsum(q1); q2 = wsum(q2);
    W0 = xgrp2(W0); W1 = xgrp2(W1); W2 = xgrp2(W2); W3 = xgrp2(W3);
    float pd = xi4.x*Gx4.x + xi4.y*Gx4.y + xi4.z*Gx4.z + xi4.w*Gx4.w;
    float di1 = q1;
    float di2 = -rsum16(pd) + q2 + gb;
    const float4 xt4 = *(const float4*)(out + rr + 4 * c);
    float rden = 1.0f / (fmaxf(di1, EPS_CLAMP) + fmaxf(di2, EPS_CLAMP));
    float o0 = (W0 + xt4.x - Gv4.x) * rden;
    float o1 = (W1 + xt4.y - Gv4.y) * rden;
    float o2 = (W2 + xt4.z - Gv4.z) * rden;
    float o3 = (W3 + xt4.w - Gv4.w) * rden;
    if (g == 0) *(float4*)(out + rr + 4 * c) = make_float4(o0, o1, o2, o3);
  }
}

extern "C" void kernel_launch(void* const* d_in, const int* in_sizes, int n_in,
                              void* d_out, int out_size, void* d_ws, size_t ws_size,
                              hipStream_t stream) {
  const float* x  = (const float*)d_in[0];
  const int*   u  = (const int*)d_in[1];
  const int*   it = (const int*)d_in[2];
  float* out = (float*)d_out;
  const int E = in_sizes[1];

  char* wsb = (char*)d_ws;
  size_t off = 0;
  auto alloc = [&](size_t elems) { void* p = wsb + off; off += elems * 4; return p; };

  // zero-init region (contiguous, first)
  int*   du     = (int*)alloc(100016);
  int*   di     = (int*)alloc(50016);
  float* sum_xi = (float*)alloc(64);
  float* sum_vi = (float*)alloc(64);
  float* Gx     = (float*)alloc(64);
  float* Gv     = (float*)alloc(64);
  float* Gb     = (float*)alloc(16);
  size_t zero_bytes = off;

  float* Smat   = (float*)alloc(4096);
  float* Tmat   = (float*)alloc(4096);
  float* part   = (float*)alloc((size_t)GRID_OUT * 4096);
  float*  inv_norm = (float*)alloc(150016);
  int*    uoff     = (int*)alloc(100016);
  int*    ioff     = (int*)alloc(50016);
  int*    ru_      = (int*)alloc(1000000);
  int*    ri_      = (int*)alloc(1000000);
  int*    uev      = (int*)alloc(1000000);
  unsigned long long* iue = (unsigned long long*)alloc(2000000);
  float*  d_raw    = (float*)alloc(1000000);
  float4* usc      = (float4*)alloc(400000);

  hipMemsetAsync(d_ws, 0, zero_bytes, stream);

  k_norm_sums<<<1024, 256, 0, stream>>>(x, inv_norm, sum_xi, sum_vi);
  k_count2<<<2048, 256, 0, stream>>>(u, it, du, di, ru_, ri_, E);
  k_scan2<<<2, 1024, 0, stream>>>(du, NU, uoff, di, NI, ioff);
  k_scatter3<<<4096, 256, 0, stream>>>(u, it, ru_, ri_, uoff, ioff, E, uev, iue);
  k_outer4<<<GRID_OUT, 256, 0, stream>>>(x, inv_norm, du, part);
  k_redST<<<32, 256, 0, stream>>>(part, Smat, Tmat);
  k_matvec<<<1536, 256, 0, stream>>>(x, inv_norm, Smat, Tmat, out, 1024);
  k_user4<<<2048, 256, 0, stream>>>(x, inv_norm, uoff, uev, sum_xi, sum_vi,
                                    d_raw, usc, out, Gx, Gv, Gb);
  k_item4<<<2048, 256, 0, stream>>>(x, inv_norm, ioff, (const uint2*)iue, d_raw, usc,
                                    Gx, Gv, Gb, out);
}